// Round 10
// baseline (77.747 us; speedup 1.0000x reference)
//
#include <hip/hip_runtime.h>
#include <math.h>

// Problem constants (B=1, H=4, N=2048, D=64, M=256)
#define NH   4
#define SEQ  2048
#define DH   64
#define NF   256
#define ROWS (NH*SEQ)                // 8192
#define DN    0.35355339059327373f   // 64^-0.25
#define DIAGC 0.0625f                // 0.5*DN*DN
#define RATIO 0.0625f                // 1/sqrt(256)
#define EPSF  1e-4f

typedef __attribute__((ext_vector_type(8))) short bf8;
typedef __attribute__((ext_vector_type(4))) short bf4;
typedef __attribute__((ext_vector_type(4))) float f4;
typedef __attribute__((ext_vector_type(2))) unsigned int u32x2;

static __device__ __forceinline__ unsigned short f2bf(float x) {
  union { float f; unsigned u; } v; v.f = x;
  unsigned r = v.u + 0x7FFF + ((v.u >> 16) & 1);
  return (unsigned short)(r >> 16);
}
static __device__ __forceinline__ float bf2f(unsigned short b) {
  union { unsigned u; float f; } v; v.u = ((unsigned)b) << 16;
  return v.f;
}

// ---------------- P -> bf16 hi/lo split (once) ----------------
__global__ __launch_bounds__(256) void fp_prep(const float* __restrict__ P,
                                               unsigned short* __restrict__ phi,
                                               unsigned short* __restrict__ plo) {
  int i = blockIdx.x*256 + threadIdx.x;   // < 16384
  float p = P[i];
  unsigned short h = f2bf(p);
  phi[i] = h;
  plo[i] = f2bf(p - bf2f(h));
}

// ---- fused projection (q: full features; k: dsh-diag fp32 + tile max) + V^T ----
// blocks 0..511: q tiles; 512..1023: k tiles; 1024..1151: V transpose.
__global__ __launch_bounds__(256) void k_proj(const float* __restrict__ q,
    const float* __restrict__ k, const float* __restrict__ v,
    const unsigned short* __restrict__ phi, const unsigned short* __restrict__ plo,
    unsigned short* __restrict__ qfb, float* __restrict__ dshd,
    float* __restrict__ bmax, unsigned short* __restrict__ vtb) {
  __shared__ float lds[64*65];
  const int b = blockIdx.x;
  if (b >= 1024) {                       // ---- V transpose: 128 blocks ----
    const int cb = b - 1024;
    const int h = cb >> 5, n0 = (cb & 31) * 64;
    const int tid = threadIdx.x;
    for (int i = tid; i < 4096; i += 256) {
      int n = i >> 6, e = i & 63;
      lds[n*65 + e] = v[((size_t)h*SEQ + n0 + n)*DH + e];
    }
    __syncthreads();
    for (int i = tid; i < 4096; i += 256) {
      int e = i >> 6, n = i & 63;
      vtb[((size_t)h*DH + e)*SEQ + n0 + n] = f2bf(lds[n*65 + e]);
    }
    return;
  }
  const bool isq = b < 512;
  const int tile = isq ? b : b - 512;    // h*128 + t
  const int w = threadIdx.x >> 6, lane = threadIdx.x & 63;
  const int lr = lane & 15, g = lane >> 4;
  const float* x = (isq ? q : k) + (size_t)tile*16*DH;

  f4 a  = *(const f4*)(x + lr*DH + g*8);
  f4 bb = *(const f4*)(x + lr*DH + g*8 + 4);
  f4 c  = *(const f4*)(x + lr*DH + 32 + g*8);
  f4 d  = *(const f4*)(x + lr*DH + 32 + g*8 + 4);
  float ss = 0.f;
#pragma unroll
  for (int i = 0; i < 4; ++i) ss += a[i]*a[i] + bb[i]*bb[i] + c[i]*c[i] + d[i]*d[i];
  ss += __shfl_xor(ss, 16);
  ss += __shfl_xor(ss, 32);              // full sum(x^2) of row lr

  bf8 xh0, xh1, xl0, xl1;
#pragma unroll
  for (int i = 0; i < 4; ++i) {
    float v0 = DN*a[i], v1 = DN*bb[i], v2 = DN*c[i], v3 = DN*d[i];
    unsigned short h0 = f2bf(v0), h1 = f2bf(v1), h2 = f2bf(v2), h3 = f2bf(v3);
    xh0[i] = (short)h0; xh0[i+4] = (short)h1;
    xh1[i] = (short)h2; xh1[i+4] = (short)h3;
    xl0[i]   = (short)f2bf(v0 - bf2f(h0)); xl0[i+4] = (short)f2bf(v1 - bf2f(h1));
    xl1[i]   = (short)f2bf(v2 - bf2f(h2)); xl1[i+4] = (short)f2bf(v3 - bf2f(h3));
  }

  const int ct0 = w*4;
  f4 dsh[4];
#pragma unroll
  for (int cc = 0; cc < 4; ++cc) {
    const int ct = ct0 + cc;
    const unsigned short* pr = phi + (ct*16 + lr)*DH + g*8;
    const unsigned short* pl = plo + (ct*16 + lr)*DH + g*8;
    bf8 bh0 = *(const bf8*)(pr);
    bf8 bh1 = *(const bf8*)(pr + 32);
    bf8 bl0 = *(const bf8*)(pl);
    bf8 bl1 = *(const bf8*)(pl + 32);
    f4 acc = {0.f, 0.f, 0.f, 0.f};
    acc = __builtin_amdgcn_mfma_f32_16x16x32_bf16(xh0, bh0, acc, 0, 0, 0);
    acc = __builtin_amdgcn_mfma_f32_16x16x32_bf16(xh1, bh1, acc, 0, 0, 0);
    acc = __builtin_amdgcn_mfma_f32_16x16x32_bf16(xh0, bl0, acc, 0, 0, 0);
    acc = __builtin_amdgcn_mfma_f32_16x16x32_bf16(xh1, bl1, acc, 0, 0, 0);
    acc = __builtin_amdgcn_mfma_f32_16x16x32_bf16(xl0, bh0, acc, 0, 0, 0);
    acc = __builtin_amdgcn_mfma_f32_16x16x32_bf16(xl1, bh1, acc, 0, 0, 0);
    dsh[cc] = acc;
  }

  f4 mr;
#pragma unroll
  for (int r = 0; r < 4; ++r)
    mr[r] = fmaxf(fmaxf(dsh[0][r], dsh[1][r]), fmaxf(dsh[2][r], dsh[3][r]));
#pragma unroll
  for (int mk = 1; mk <= 8; mk <<= 1) {
#pragma unroll
    for (int r = 0; r < 4; ++r) mr[r] = fmaxf(mr[r], __shfl_xor(mr[r], mk));
  }
  if (lr == 0) {
#pragma unroll
    for (int r = 0; r < 4; ++r) lds[w*16 + 4*g + r] = mr[r];
  }
  __syncthreads();
  float rm[4], sr[4];
#pragma unroll
  for (int r = 0; r < 4; ++r) {
    rm[r] = fmaxf(fmaxf(lds[0*16 + 4*g + r], lds[1*16 + 4*g + r]),
                  fmaxf(lds[2*16 + 4*g + r], lds[3*16 + 4*g + r]));
    sr[r] = __shfl(ss, 4*g + r);
  }

  if (isq) {
    unsigned short* ob = qfb + (size_t)tile*16*NF;
#pragma unroll
    for (int cc = 0; cc < 4; ++cc) {
#pragma unroll
      for (int r = 0; r < 4; ++r)
        ob[(4*g + r)*NF + (ct0 + cc)*16 + lr] =
            f2bf(RATIO*(expf(dsh[cc][r] - (sr[r]*DIAGC + rm[r])) + EPSF));
    }
  } else {
    float* db = dshd + (size_t)tile*16*NF;
#pragma unroll
    for (int cc = 0; cc < 4; ++cc) {
#pragma unroll
      for (int r = 0; r < 4; ++r)
        db[(4*g + r)*NF + (ct0 + cc)*16 + lr] = dsh[cc][r] - sr[r]*DIAGC;
    }
    // per-TILE max (512 entries): reduce rm over rows
    float tmax = fmaxf(fmaxf(rm[0], rm[1]), fmaxf(rm[2], rm[3]));
    tmax = fmaxf(tmax, __shfl_xor(tmax, 16));
    tmax = fmaxf(tmax, __shfl_xor(tmax, 32));
    if (w == 0 && lane == 0) bmax[tile] = tmax;
  }
}

// ---- k_feat: gmax (512-entry) + exp -> kfb bf16 + kft (m-major) + csumT ----
__global__ __launch_bounds__(256) void k_feat2(const float* __restrict__ dshd,
    const float* __restrict__ bmax, unsigned short* __restrict__ kfb,
    unsigned short* __restrict__ kft, float* __restrict__ csumT) {
  const int u = blockIdx.x, m = threadIdx.x;     // u: 0..511 = h*128 + t
  const int h = u >> 7, t = u & 127;
  __shared__ float red[256];
  red[m] = fmaxf(bmax[m], bmax[m + 256]);
  __syncthreads();
  for (int s = 128; s > 0; s >>= 1) {
    if (m < s) red[m] = fmaxf(red[m], red[m+s]);
    __syncthreads();
  }
  const float gg = red[0];
  const float* db = dshd + (size_t)u*16*NF + m;
  unsigned short* ob = kfb + (size_t)u*16*NF + m;
  float run = 0.f;
  bf8 k0, k1;
#pragma unroll
  for (int r = 0; r < 16; ++r) {
    unsigned short bv = f2bf(RATIO*(expf(db[r*NF] - gg) + EPSF));
    ob[r*NF] = bv;
    if (r < 8) k0[r] = (short)bv; else k1[r-8] = (short)bv;
    run += bf2f(bv);
  }
  csumT[((size_t)(h*NF + m))*128 + t] = run;
  unsigned short* kt = kft + ((size_t)(h*NF + m))*SEQ + t*16;
  *(bf8*)kt = k0;
  *(bf8*)(kt + 8) = k1;
}

// ---- fused state build + exclusive cumsum -> hi/lo bf16; 1 wave per block ----
// block-unit = (h, et, mt): one 16(e)x16(m) tile, walks 16 chunks.
__global__ __launch_bounds__(64) void k_state(
    const unsigned short* __restrict__ vtb, const unsigned short* __restrict__ kft,
    unsigned short* __restrict__ sthi, unsigned short* __restrict__ stlo) {
  const int lane = threadIdx.x;              // 0..63
  const int lr = lane & 15, g = lane >> 4;
  const int unit = blockIdx.x;               // 0..63
  const int h = blockIdx.y;
  const int et = unit >> 4, mt = unit & 15;

  const unsigned short* vb = vtb + ((size_t)(h*DH + et*16 + lr))*SEQ;
  const unsigned short* kb = kft + ((size_t)(h*NF + mt*16 + lr))*SEQ;

  f4 cum = {0.f, 0.f, 0.f, 0.f};
  for (int c = 0; c < 16; ++c) {
    const size_t base = ((size_t)((h*16 + c)*64 + et*16 + 4*g))*NF + mt*16 + lr;
#pragma unroll
    for (int r = 0; r < 4; ++r) {
      unsigned short hi = f2bf(cum[r]);
      sthi[base + (size_t)r*NF] = hi;
      stlo[base + (size_t)r*NF] = f2bf(cum[r] - bf2f(hi));
    }
#pragma unroll
    for (int ks = 0; ks < 4; ++ks) {
      const int j0 = c*128 + ks*32 + g*8;
      bf8 xv = *(const bf8*)(vb + j0);
      bf8 ym = *(const bf8*)(kb + j0);
      cum = __builtin_amdgcn_mfma_f32_16x16x32_bf16(xv, ym, cum, 0, 0, 0);
    }
  }
}

// ---- chunked causal attention with per-wave q'-divide prologue ----
// block = (h, chunk, half): 32 blocks/head; 4 waves = 4 row-tiles.
__global__ __launch_bounds__(256) void k_attn3(const unsigned short* __restrict__ qfb,
                                               const unsigned short* __restrict__ kfb,
                                               const unsigned short* __restrict__ vtb,
                                               const unsigned short* __restrict__ sthi,
                                               const unsigned short* __restrict__ stlo,
                                               const float* __restrict__ csumT,
                                               float* __restrict__ out) {
  const int h = blockIdx.y;
  const int b = blockIdx.x;            // 0..31
  const int c = b >> 1, half = b & 1;  // chunk 0..15
  const int wid = threadIdx.x >> 6, lane = threadIdx.x & 63;
  const int lr = lane & 15, g = lane >> 4;
  const int row0 = c*128 + half*64;    // this block's 64 contiguous rows
  const int tile0 = c*8 + half*4;
  const int t = tile0 + wid;           // this wave's row-tile
  const int jc0 = c*8;
  const int nstage = half*4 + 4;

  __shared__ __align__(16) char smem[43008];
  unsigned short* Ks = (unsigned short*)(smem + 32768);  // 8KB, XOR-swizzled
  unsigned short* Vs = (unsigned short*)(smem + 40960);  // 2KB
  // Qs: bytes [0,32768): 64 rows x 256 m bf16, XOR-swizzled

  // ---- per-wave prime: q' for this wave's 16 rows (4 chains of 16 per lane) ----
  {
    const int tprev = tile0 + wid;       // tiles before this wave's rows
    float run[4];
    const float* ctp = csumT + ((size_t)h*NF)*128;
#pragma unroll
    for (int mb = 0; mb < 4; ++mb) {
      const float* cp = ctp + (size_t)(mb*64 + lane)*128;
      float s0 = 0.f, s1 = 0.f, s2 = 0.f, s3 = 0.f;
      int c2 = 0;
      for (; c2 + 4 <= tprev; c2 += 4) {
        f4 vv = *(const f4*)(cp + c2);
        s0 += vv[0]; s1 += vv[1]; s2 += vv[2]; s3 += vv[3];
      }
      float s = (s0 + s1) + (s2 + s3);
      for (; c2 < tprev; ++c2) s += cp[c2];
      run[mb] = s;
    }
    const int rbase = row0 + wid*16;
    const unsigned short* kfp = kfb + ((size_t)(h*SEQ + rbase))*NF;
    const unsigned short* qfp = qfb + ((size_t)(h*SEQ + rbase))*NF;
#pragma unroll
    for (int rr = 0; rr < 16; ++rr) {
#pragma unroll
      for (int mb = 0; mb < 4; ++mb) {
        const int m = mb*64 + lane;
        run[mb] += bf2f(kfp[(size_t)rr*NF + m]);
        float qv = bf2f(qfp[(size_t)rr*NF + m]) / run[mb];
        const int r = wid*16 + rr;
        const int byte = (r*512 + m*2) ^ ((r & 7) << 4);
        *(unsigned short*)(smem + byte) = f2bf(qv);
      }
    }
  }
  __syncthreads();

  // Q' A-fragments from swizzled LDS (each wave reads its own rows)
  bf8 qf[8];
  {
    const int rloc = wid*16 + lr;
#pragma unroll
    for (int kb = 0; kb < 8; ++kb) {
      const int byte = (rloc*512 + g*16 + kb*64) ^ ((rloc & 7) << 4);
      qf[kb] = *(const bf8*)(smem + byte);
    }
  }

  const char* kTile = (const char*)(kfb + (size_t)h*SEQ*NF);
  const char* vTile = (const char*)(vtb + (size_t)h*DH*SEQ);

  const int ko0 = (wid*2 + 0)*1024 + lane*16;
  const int ko1 = (wid*2 + 1)*1024 + lane*16;
  const int kw0 = ko0 ^ (((ko0 >> 9) & 7) << 4);
  const int kw1 = ko1 ^ (((ko1 >> 9) & 7) << 4);
  const int vo = wid*512 + lane*8;
  const int ve = vo >> 5;
  const int vn = vo & 31;

  f4 sk0, sk1; u32x2 sv;
  {  // issue staging loads for first j-tile (fly under inter-GEMM)
    const char* kt = kTile + (size_t)jc0*8192;
    sk0 = *(const f4*)(kt + ko0);
    sk1 = *(const f4*)(kt + ko1);
    sv  = *(const u32x2*)(vTile + (size_t)ve*4096 + (size_t)jc0*32 + vn);
  }

  // ---- inter-chunk: O = q' x cumstate (hi/lo split) ----
  f4 o0 = {0,0,0,0}, o1 = {0,0,0,0}, o2 = {0,0,0,0}, o3 = {0,0,0,0};
  {
    const unsigned short* SH = sthi + ((size_t)((h*16 + c)*64 + lr))*NF + g*8;
    const unsigned short* SL = stlo + ((size_t)((h*16 + c)*64 + lr))*NF + g*8;
#pragma unroll
    for (int ks = 0; ks < 8; ++ks) {
#pragma unroll
      for (int et = 0; et < 4; ++et) {
        bf8 bh = *(const bf8*)(SH + et*16*NF + ks*32);
        bf8 bl = *(const bf8*)(SL + et*16*NF + ks*32);
        f4 acc = (et == 0) ? o0 : (et == 1) ? o1 : (et == 2) ? o2 : o3;
        acc = __builtin_amdgcn_mfma_f32_16x16x32_bf16(qf[ks], bh, acc, 0, 0, 0);
        acc = __builtin_amdgcn_mfma_f32_16x16x32_bf16(qf[ks], bl, acc, 0, 0, 0);
        if (et == 0) o0 = acc; else if (et == 1) o1 = acc; else if (et == 2) o2 = acc; else o3 = acc;
      }
    }
  }

  // ---- intra-chunk causal sweep over staged K/V tiles ----
  for (int jj = 0; jj < nstage; ++jj) {
    const int j = jc0 + jj;
    *(f4*)((char*)Ks + kw0) = sk0;
    *(f4*)((char*)Ks + kw1) = sk1;
    *(u32x2*)((char*)Vs + vo) = sv;
    __syncthreads();
    if (jj + 1 < nstage) {
      const char* kt = kTile + (size_t)(j+1)*8192;
      sk0 = *(const f4*)(kt + ko0);
      sk1 = *(const f4*)(kt + ko1);
      sv  = *(const u32x2*)(vTile + (size_t)ve*4096 + (size_t)(j+1)*32 + vn);
    }
    if (j <= t) {
      bf8 kcs[8];
#pragma unroll
      for (int kb = 0; kb < 8; ++kb) {
        int off = (lr*512 + kb*64 + g*16) ^ ((lr & 7) << 4);
        kcs[kb] = *(const bf8*)((const char*)Ks + off);
      }
      f4 st = {0,0,0,0};
#pragma unroll
      for (int kb = 0; kb < 8; ++kb)
        st = __builtin_amdgcn_mfma_f32_16x16x32_bf16(kcs[kb], qf[kb], st, 0, 0, 0);
      if (j == t) {
#pragma unroll
        for (int rr = 0; rr < 4; ++rr) if (g*4 + rr > lr) st[rr] = 0.f;
      }
      bf8 sb = { (short)f2bf(st[0]), (short)f2bf(st[1]), (short)f2bf(st[2]), (short)f2bf(st[3]),
                 (short)0, (short)0, (short)0, (short)0 };
#pragma unroll
      for (int eb = 0; eb < 4; ++eb) {
        bf4 v4 = *(const bf4*)((const char*)Vs + (eb*16 + lr)*32 + g*8);
        bf8 vf = { v4[0], v4[1], v4[2], v4[3], (short)0, (short)0, (short)0, (short)0 };
        f4 acc = (eb == 0) ? o0 : (eb == 1) ? o1 : (eb == 2) ? o2 : o3;
        acc = __builtin_amdgcn_mfma_f32_16x16x32_bf16(sb, vf, acc, 0, 0, 0);
        if (eb == 0) o0 = acc; else if (eb == 1) o1 = acc; else if (eb == 2) o2 = acc; else o3 = acc;
      }
    }
    __syncthreads();
  }

  float* ob = out + ((size_t)(h*SEQ + t*16))*DH;
#pragma unroll
  for (int rr = 0; rr < 4; ++rr) {
    ob[(size_t)(4*g + rr)*DH +  0 + lr] = o0[rr];
    ob[(size_t)(4*g + rr)*DH + 16 + lr] = o1[rr];
    ob[(size_t)(4*g + rr)*DH + 32 + lr] = o2[rr];
    ob[(size_t)(4*g + rr)*DH + 48 + lr] = o3[rr];
  }
}

extern "C" void kernel_launch(void* const* d_in, const int* in_sizes, int n_in,
                              void* d_out, int out_size, void* d_ws, size_t ws_size,
                              hipStream_t stream) {
  const float* q = (const float*)d_in[0];
  const float* k = (const float*)d_in[1];
  const float* v = (const float*)d_in[2];
  const float* P = (const float*)d_in[3];
  float* out = (float*)d_out;

  char* ws = (char*)d_ws;                                    // 256 MiB available
  unsigned short* qfb  = (unsigned short*)(ws);              // 4 MB
  unsigned short* kfb  = (unsigned short*)(ws + (4u<<20));   // 4 MB
  unsigned short* vtb  = (unsigned short*)(ws + (8u<<20));   // 1 MB
  unsigned short* kft  = (unsigned short*)(ws + (12u<<20));  // 4 MB (m-major kf)
  float* dshd   = (float*)(ws + (16u<<20));                  // 8 MB
  float* bmax   = (float*)(ws + (24u<<20));                  // 2 KB (512 tiles)
  float* csumT  = (float*)(ws + (25u<<20));                  // 512 KB [h][m][tile]
  unsigned short* sthi = (unsigned short*)(ws + (33u<<20));  // 2 MB
  unsigned short* stlo = (unsigned short*)(ws + (36u<<20));  // 2 MB
  unsigned short* phi  = (unsigned short*)(ws + (40u<<20));          // 32 KB
  unsigned short* plo  = (unsigned short*)(ws + (40u<<20) + 32768);  // 32 KB

  fp_prep <<<64, 256, 0, stream>>>(P, phi, plo);
  k_proj  <<<1152, 256, 0, stream>>>(q, k, v, phi, plo, qfb, dshd, bmax, vtb);
  k_feat2 <<<512, 256, 0, stream>>>(dshd, bmax, kfb, kft, csumT);
  k_state <<<dim3(64, NH), 64, 0, stream>>>(vtb, kft, sthi, stlo);
  k_attn3 <<<dim3(32, NH), 256, 0, stream>>>(qfb, kfb, vtb, sthi, stlo, csumT, out);
}

// Round 11
// 61.089 us; speedup vs baseline: 1.2727x; 1.2727x over previous
//
#include <hip/hip_runtime.h>
#include <math.h>

// Problem constants (B=1, H=4, N=2048, D=64, M=256)
#define NH   4
#define SEQ  2048
#define DH   64
#define NF   256
#define ROWS (NH*SEQ)                // 8192
#define DN    0.35355339059327373f   // 64^-0.25
#define DIAGC 0.0625f                // 0.5*DN*DN
#define RATIO 0.0625f                // 1/sqrt(256)
#define EPSF  1e-4f

typedef __attribute__((ext_vector_type(8))) short bf8;
typedef __attribute__((ext_vector_type(4))) short bf4;
typedef __attribute__((ext_vector_type(4))) float f4;

static __device__ __forceinline__ unsigned short f2bf(float x) {
  union { float f; unsigned u; } v; v.f = x;
  unsigned r = v.u + 0x7FFF + ((v.u >> 16) & 1);
  return (unsigned short)(r >> 16);
}
static __device__ __forceinline__ float bf2f(unsigned short b) {
  union { unsigned u; float f; } v; v.u = ((unsigned)b) << 16;
  return v.f;
}

// ---- fused projection (q: full features; k: dsh-diag fp32 + rowmax) + V^T ----
// blocks 0..511: q tiles; 512..1023: k tiles; 1024..1151: V transpose.  (R7 verbatim)
__global__ __launch_bounds__(256) void k_proj(const float* __restrict__ q,
    const float* __restrict__ k, const float* __restrict__ v,
    const float* __restrict__ P,
    unsigned short* __restrict__ qfb, float* __restrict__ dshd,
    float* __restrict__ bmax, unsigned short* __restrict__ vtb) {
  __shared__ float lds[64*65];
  const int b = blockIdx.x;
  if (b >= 1024) {                       // ---- V transpose: 128 blocks ----
    const int cb = b - 1024;
    const int h = cb >> 5, n0 = (cb & 31) * 64;
    const int tid = threadIdx.x;
    for (int i = tid; i < 4096; i += 256) {
      int n = i >> 6, e = i & 63;
      lds[n*65 + e] = v[((size_t)h*SEQ + n0 + n)*DH + e];
    }
    __syncthreads();
    for (int i = tid; i < 4096; i += 256) {
      int e = i >> 6, n = i & 63;
      vtb[((size_t)h*DH + e)*SEQ + n0 + n] = f2bf(lds[n*65 + e]);
    }
    return;
  }
  const bool isq = b < 512;
  const int tile = isq ? b : b - 512;    // h*128 + t
  const int w = threadIdx.x >> 6, lane = threadIdx.x & 63;
  const int lr = lane & 15, g = lane >> 4;
  const float* x = (isq ? q : k) + (size_t)tile*16*DH;

  f4 a  = *(const f4*)(x + lr*DH + g*8);
  f4 bb = *(const f4*)(x + lr*DH + g*8 + 4);
  f4 c  = *(const f4*)(x + lr*DH + 32 + g*8);
  f4 d  = *(const f4*)(x + lr*DH + 32 + g*8 + 4);
  float ss = 0.f;
#pragma unroll
  for (int i = 0; i < 4; ++i) ss += a[i]*a[i] + bb[i]*bb[i] + c[i]*c[i] + d[i]*d[i];
  ss += __shfl_xor(ss, 16);
  ss += __shfl_xor(ss, 32);              // full sum(x^2) of row lr

  bf8 xh0, xh1, xl0, xl1;
#pragma unroll
  for (int i = 0; i < 4; ++i) {
    float v0 = DN*a[i], v1 = DN*bb[i], v2 = DN*c[i], v3 = DN*d[i];
    unsigned short h0 = f2bf(v0), h1 = f2bf(v1), h2 = f2bf(v2), h3 = f2bf(v3);
    xh0[i] = (short)h0; xh0[i+4] = (short)h1;
    xh1[i] = (short)h2; xh1[i+4] = (short)h3;
    xl0[i]   = (short)f2bf(v0 - bf2f(h0)); xl0[i+4] = (short)f2bf(v1 - bf2f(h1));
    xl1[i]   = (short)f2bf(v2 - bf2f(h2)); xl1[i+4] = (short)f2bf(v3 - bf2f(h3));
  }

  const int ct0 = w*4;
  f4 dsh[4];
#pragma unroll
  for (int cc = 0; cc < 4; ++cc) {
    const int ct = ct0 + cc;
    const float* prow = P + (ct*16 + lr)*DH + g*8;
    f4 p0 = *(const f4*)(prow);
    f4 p1 = *(const f4*)(prow + 4);
    f4 p2 = *(const f4*)(prow + 32);
    f4 p3 = *(const f4*)(prow + 36);
    bf8 bh0, bl0, bh1, bl1;
#pragma unroll
    for (int i = 0; i < 4; ++i) {
      unsigned short h0 = f2bf(p0[i]), h1 = f2bf(p1[i]);
      unsigned short h2 = f2bf(p2[i]), h3 = f2bf(p3[i]);
      bh0[i] = (short)h0; bh0[i+4] = (short)h1;
      bh1[i] = (short)h2; bh1[i+4] = (short)h3;
      bl0[i]   = (short)f2bf(p0[i] - bf2f(h0)); bl0[i+4] = (short)f2bf(p1[i] - bf2f(h1));
      bl1[i]   = (short)f2bf(p2[i] - bf2f(h2)); bl1[i+4] = (short)f2bf(p3[i] - bf2f(h3));
    }
    f4 acc = {0.f, 0.f, 0.f, 0.f};
    acc = __builtin_amdgcn_mfma_f32_16x16x32_bf16(xh0, bh0, acc, 0, 0, 0);
    acc = __builtin_amdgcn_mfma_f32_16x16x32_bf16(xh1, bh1, acc, 0, 0, 0);
    acc = __builtin_amdgcn_mfma_f32_16x16x32_bf16(xh0, bl0, acc, 0, 0, 0);
    acc = __builtin_amdgcn_mfma_f32_16x16x32_bf16(xh1, bl1, acc, 0, 0, 0);
    acc = __builtin_amdgcn_mfma_f32_16x16x32_bf16(xl0, bh0, acc, 0, 0, 0);
    acc = __builtin_amdgcn_mfma_f32_16x16x32_bf16(xl1, bh1, acc, 0, 0, 0);
    dsh[cc] = acc;
  }

  f4 mr;
#pragma unroll
  for (int r = 0; r < 4; ++r)
    mr[r] = fmaxf(fmaxf(dsh[0][r], dsh[1][r]), fmaxf(dsh[2][r], dsh[3][r]));
#pragma unroll
  for (int mk = 1; mk <= 8; mk <<= 1) {
#pragma unroll
    for (int r = 0; r < 4; ++r) mr[r] = fmaxf(mr[r], __shfl_xor(mr[r], mk));
  }
  if (lr == 0) {
#pragma unroll
    for (int r = 0; r < 4; ++r) lds[w*16 + 4*g + r] = mr[r];
  }
  __syncthreads();
  float rm[4], sr[4];
#pragma unroll
  for (int r = 0; r < 4; ++r) {
    rm[r] = fmaxf(fmaxf(lds[0*16 + 4*g + r], lds[1*16 + 4*g + r]),
                  fmaxf(lds[2*16 + 4*g + r], lds[3*16 + 4*g + r]));
    sr[r] = __shfl(ss, 4*g + r);
  }

  if (isq) {
    unsigned short* ob = qfb + (size_t)tile*16*NF;
#pragma unroll
    for (int cc = 0; cc < 4; ++cc) {
#pragma unroll
      for (int r = 0; r < 4; ++r)
        ob[(4*g + r)*NF + (ct0 + cc)*16 + lr] =
            f2bf(RATIO*(expf(dsh[cc][r] - (sr[r]*DIAGC + rm[r])) + EPSF));
    }
  } else {
    float* db = dshd + (size_t)tile*16*NF;
#pragma unroll
    for (int cc = 0; cc < 4; ++cc) {
#pragma unroll
      for (int r = 0; r < 4; ++r)
        db[(4*g + r)*NF + (ct0 + cc)*16 + lr] = dsh[cc][r] - sr[r]*DIAGC;
    }
    if (w == 0 && lr == 0) {
#pragma unroll
      for (int r = 0; r < 4; ++r) bmax[tile*16 + 4*g + r] = mr[r];
    }
  }
}

// ---- k_feat: gmax (inline) + exp -> kfb bf16 + kft (m-major) + tile sums ----
// (R7 verbatim)
__global__ __launch_bounds__(256) void k_feat2(const float* __restrict__ dshd,
    const float* __restrict__ bmax, unsigned short* __restrict__ kfb,
    unsigned short* __restrict__ kft, float* __restrict__ csum) {
  const int u = blockIdx.x, m = threadIdx.x;     // u: 0..511 = h*128 + t
  const int h = u >> 7, t = u & 127;
  __shared__ float red[256];
  float mx = -3.4e38f;
  for (int i = m; i < ROWS; i += 256) mx = fmaxf(mx, bmax[i]);
  red[m] = mx;
  __syncthreads();
  for (int s = 128; s > 0; s >>= 1) {
    if (m < s) red[m] = fmaxf(red[m], red[m+s]);
    __syncthreads();
  }
  const float gg = red[0];
  const float* db = dshd + (size_t)u*16*NF + m;
  unsigned short* ob = kfb + (size_t)u*16*NF + m;
  float run = 0.f;
  bf8 k0, k1;
#pragma unroll
  for (int r = 0; r < 16; ++r) {
    unsigned short bv = f2bf(RATIO*(expf(db[r*NF] - gg) + EPSF));
    ob[r*NF] = bv;
    if (r < 8) k0[r] = (short)bv; else k1[r-8] = (short)bv;
    run += bf2f(bv);
  }
  csum[(size_t)u*NF + m] = run;
  unsigned short* kt = kft + ((size_t)(h*NF + m))*SEQ + t*16;
  *(bf8*)kt = k0;
  *(bf8*)(kt + 8) = k1;
}

// ---- per-chunk state build: 1 wave/block, 256 blocks (regrid of R7 body) ----
// block = (c*4 + mt-group, h): stateT[e][m] partial for mt in [4*mtg, 4*mtg+4)
__global__ __launch_bounds__(64) void k_state_build(
    const unsigned short* __restrict__ vtb, const unsigned short* __restrict__ kft,
    float* __restrict__ stateP) {
  const int lane = threadIdx.x;
  const int lr = lane & 15, g = lane >> 4;
  const int c = blockIdx.x >> 2, mtg = blockIdx.x & 3;
  const int h = blockIdx.y;
  f4 acc[4][4];   // [et][mt]
#pragma unroll
  for (int et = 0; et < 4; ++et)
#pragma unroll
    for (int mt = 0; mt < 4; ++mt) acc[et][mt] = (f4){0.f,0.f,0.f,0.f};

#pragma unroll
  for (int ks = 0; ks < 4; ++ks) {
    const int j0 = c*128 + ks*32 + g*8;
    bf8 xv[4], ym[4];
#pragma unroll
    for (int et = 0; et < 4; ++et)
      xv[et] = *(const bf8*)(vtb + ((size_t)(h*DH + et*16 + lr))*SEQ + j0);
#pragma unroll
    for (int mt = 0; mt < 4; ++mt)
      ym[mt] = *(const bf8*)(kft + ((size_t)(h*NF + (4*mtg + mt)*16 + lr))*SEQ + j0);
#pragma unroll
    for (int et = 0; et < 4; ++et)
#pragma unroll
      for (int mt = 0; mt < 4; ++mt)
        acc[et][mt] = __builtin_amdgcn_mfma_f32_16x16x32_bf16(xv[et], ym[mt], acc[et][mt], 0, 0, 0);
  }
  float* sp = stateP + (size_t)(h*16 + c)*64*NF;
#pragma unroll
  for (int et = 0; et < 4; ++et)
#pragma unroll
    for (int mt = 0; mt < 4; ++mt)
#pragma unroll
      for (int r = 0; r < 4; ++r)
        sp[(size_t)(et*16 + 4*g + r)*NF + (4*mtg + mt)*16 + lr] = acc[et][mt][r];
}

// ---- exclusive cumsum of chunk states -> hi/lo + csum exclusive scan ----
// blocks 0..63: e-row state scan; block 64: csum scan for head h.
__global__ __launch_bounds__(64) void k_state_scan(const float* __restrict__ stateP,
    unsigned short* __restrict__ sthi, unsigned short* __restrict__ stlo,
    float* __restrict__ csum) {
  const int h = blockIdx.y;
  if (blockIdx.x == 64) {                // csum exclusive scan (in place)
    const int m0 = threadIdx.x * 4;
    f4 run = {0.f, 0.f, 0.f, 0.f};
#pragma unroll 4
    for (int c = 0; c < 128; ++c) {
      float* p = csum + ((size_t)(h*128 + c))*NF + m0;
      f4 x = *(const f4*)p;
      *(f4*)p = run;
      run += x;
    }
    return;
  }
  const int e = blockIdx.x;              // 0..63
  const int m0 = threadIdx.x * 4;
  f4 run = {0.f, 0.f, 0.f, 0.f};
  for (int c = 0; c < 16; ++c) {
    const size_t idx = (size_t)((h*16 + c)*64 + e)*NF + m0;
    unsigned short hi[4], lo[4];
#pragma unroll
    for (int i = 0; i < 4; ++i) {
      hi[i] = f2bf(run[i]);
      lo[i] = f2bf(run[i] - bf2f(hi[i]));
    }
    *(bf4*)(sthi + idx) = *(bf4*)hi;
    *(bf4*)(stlo + idx) = *(bf4*)lo;
    run += *(const f4*)(stateP + idx);
  }
}

// ---- q' = q_feat / cumsum(k_feat): O(1) prefix (csum pre-scanned) ----
__global__ __launch_bounds__(256) void k_prime2(unsigned short* __restrict__ qfb,
    const unsigned short* __restrict__ kfb, const float* __restrict__ csum) {
  const int u = blockIdx.x, m = threadIdx.x;     // u = h*128 + t
  float run = csum[(size_t)u*NF + m];            // exclusive prefix of tile sums
#pragma unroll
  for (int r = 0; r < 16; ++r) {
    size_t idx = (size_t)(u*16 + r)*NF + m;
    run += bf2f(kfb[idx]);
    qfb[idx] = f2bf(bf2f(qfb[idx]) / run);
  }
}

// ---- chunked causal attention: quarter-chunk blocks, 2 waves, 256 blocks ----
// block = (h, chunk, quarter): t = c*8 + qt*2 + wid; stages nstage = qt*2+2 tiles.
__global__ __launch_bounds__(128) void k_attn2(const unsigned short* __restrict__ qpb,
                                               const unsigned short* __restrict__ kfb,
                                               const unsigned short* __restrict__ vtb,
                                               const unsigned short* __restrict__ sthi,
                                               const unsigned short* __restrict__ stlo,
                                               float* __restrict__ out) {
  const int h = blockIdx.y;
  const int b = blockIdx.x;            // 0..63
  const int c = b >> 2, qt = b & 3;    // chunk 0..15, quarter 0..3
  const int tid = threadIdx.x;
  const int wid = tid >> 6, lane = tid & 63;
  const int t = c*8 + qt*2 + wid;      // this wave's row-tile (0..127)
  const int lr = lane & 15, g = lane >> 4;
  const int jc0 = c*8;
  const int nstage = qt*2 + 2;

  __shared__ unsigned short Ks[4096];  // 16 rows x 256 feats, XOR-swizzled
  __shared__ unsigned short Vs[1024];  // 64 e x 16 n

  // Q' A-fragments
  const unsigned short* qb = qpb + ((size_t)(h*SEQ + t*16 + lr))*NF + g*8;
  bf8 qf[8];
#pragma unroll
  for (int kb = 0; kb < 8; ++kb) qf[kb] = *(const bf8*)(qb + kb*32);

  const char* kTile = (const char*)(kfb + (size_t)h*SEQ*NF);
  const char* vTile = (const char*)(vtb + (size_t)h*DH*SEQ);

  // staging offsets: 128 threads x 64B = 8KB K-tile; 128 x 16B = 2KB V-tile
  const int ko0 = wid*4096 +    0 + lane*16;
  const int ko1 = wid*4096 + 1024 + lane*16;
  const int ko2 = wid*4096 + 2048 + lane*16;
  const int ko3 = wid*4096 + 3072 + lane*16;
  const int kw0 = ko0 ^ (((ko0 >> 9) & 7) << 4);
  const int kw1 = ko1 ^ (((ko1 >> 9) & 7) << 4);
  const int kw2 = ko2 ^ (((ko2 >> 9) & 7) << 4);
  const int kw3 = ko3 ^ (((ko3 >> 9) & 7) << 4);
  const int vo = tid*16;               // V LDS byte offset
  const int ve = vo >> 5;              // e row (0..63)
  const int vn = vo & 31;              // byte within 32B n-row

  f4 sk0, sk1, sk2, sk3, sv;
  {  // prologue: issue staging loads for first j-tile (fly under inter-GEMM)
    const char* kt = kTile + (size_t)jc0*8192;
    sk0 = *(const f4*)(kt + ko0);
    sk1 = *(const f4*)(kt + ko1);
    sk2 = *(const f4*)(kt + ko2);
    sk3 = *(const f4*)(kt + ko3);
    sv  = *(const f4*)(vTile + (size_t)ve*4096 + (size_t)jc0*32 + vn);
  }

  // ---- inter-chunk: O = q' x cumstate (hi/lo split) ----
  f4 o0 = {0,0,0,0}, o1 = {0,0,0,0}, o2 = {0,0,0,0}, o3 = {0,0,0,0};
  {
    const unsigned short* SH = sthi + ((size_t)((h*16 + c)*64 + lr))*NF + g*8;
    const unsigned short* SL = stlo + ((size_t)((h*16 + c)*64 + lr))*NF + g*8;
#pragma unroll
    for (int ks = 0; ks < 8; ++ks) {
#pragma unroll
      for (int et = 0; et < 4; ++et) {
        bf8 bh = *(const bf8*)(SH + et*16*NF + ks*32);
        bf8 bl = *(const bf8*)(SL + et*16*NF + ks*32);
        f4 acc = (et == 0) ? o0 : (et == 1) ? o1 : (et == 2) ? o2 : o3;
        acc = __builtin_amdgcn_mfma_f32_16x16x32_bf16(qf[ks], bh, acc, 0, 0, 0);
        acc = __builtin_amdgcn_mfma_f32_16x16x32_bf16(qf[ks], bl, acc, 0, 0, 0);
        if (et == 0) o0 = acc; else if (et == 1) o1 = acc; else if (et == 2) o2 = acc; else o3 = acc;
      }
    }
  }

  // ---- intra-chunk causal sweep over staged K/V tiles ----
  for (int jj = 0; jj < nstage; ++jj) {
    const int j = jc0 + jj;
    *(f4*)((char*)Ks + kw0) = sk0;
    *(f4*)((char*)Ks + kw1) = sk1;
    *(f4*)((char*)Ks + kw2) = sk2;
    *(f4*)((char*)Ks + kw3) = sk3;
    *(f4*)((char*)Vs + vo) = sv;
    __syncthreads();
    if (jj + 1 < nstage) {
      const char* kt = kTile + (size_t)(j+1)*8192;
      sk0 = *(const f4*)(kt + ko0);
      sk1 = *(const f4*)(kt + ko1);
      sk2 = *(const f4*)(kt + ko2);
      sk3 = *(const f4*)(kt + ko3);
      sv  = *(const f4*)(vTile + (size_t)ve*4096 + (size_t)(j+1)*32 + vn);
    }
    if (j <= t) {
      bf8 kcs[8];
#pragma unroll
      for (int kb = 0; kb < 8; ++kb) {
        int off = (lr*512 + kb*64 + g*16) ^ ((lr & 7) << 4);
        kcs[kb] = *(const bf8*)((const char*)Ks + off);
      }
      f4 st = {0,0,0,0};
#pragma unroll
      for (int kb = 0; kb < 8; ++kb)
        st = __builtin_amdgcn_mfma_f32_16x16x32_bf16(kcs[kb], qf[kb], st, 0, 0, 0);
      if (j == t) {
#pragma unroll
        for (int rr = 0; rr < 4; ++rr) if (g*4 + rr > lr) st[rr] = 0.f;
      }
      bf8 sb = { (short)f2bf(st[0]), (short)f2bf(st[1]), (short)f2bf(st[2]), (short)f2bf(st[3]),
                 (short)0, (short)0, (short)0, (short)0 };
#pragma unroll
      for (int eb = 0; eb < 4; ++eb) {
        bf4 v4 = *(const bf4*)((const char*)Vs + (eb*16 + lr)*32 + g*8);
        bf8 vf = { v4[0], v4[1], v4[2], v4[3], (short)0, (short)0, (short)0, (short)0 };
        f4 acc = (eb == 0) ? o0 : (eb == 1) ? o1 : (eb == 2) ? o2 : o3;
        acc = __builtin_amdgcn_mfma_f32_16x16x32_bf16(sb, vf, acc, 0, 0, 0);
        if (eb == 0) o0 = acc; else if (eb == 1) o1 = acc; else if (eb == 2) o2 = acc; else o3 = acc;
      }
    }
    __syncthreads();
  }

  float* ob = out + ((size_t)(h*SEQ + t*16))*DH;
#pragma unroll
  for (int rr = 0; rr < 4; ++rr) {
    ob[(size_t)(4*g + rr)*DH +  0 + lr] = o0[rr];
    ob[(size_t)(4*g + rr)*DH + 16 + lr] = o1[rr];
    ob[(size_t)(4*g + rr)*DH + 32 + lr] = o2[rr];
    ob[(size_t)(4*g + rr)*DH + 48 + lr] = o3[rr];
  }
}

extern "C" void kernel_launch(void* const* d_in, const int* in_sizes, int n_in,
                              void* d_out, int out_size, void* d_ws, size_t ws_size,
                              hipStream_t stream) {
  const float* q = (const float*)d_in[0];
  const float* k = (const float*)d_in[1];
  const float* v = (const float*)d_in[2];
  const float* P = (const float*)d_in[3];
  float* out = (float*)d_out;

  char* ws = (char*)d_ws;                                    // 256 MiB available
  unsigned short* qfb  = (unsigned short*)(ws);              // 4 MB
  unsigned short* kfb  = (unsigned short*)(ws + (4u<<20));   // 4 MB
  unsigned short* vtb  = (unsigned short*)(ws + (8u<<20));   // 1 MB
  unsigned short* kft  = (unsigned short*)(ws + (12u<<20));  // 4 MB (m-major kf)
  float* dshd   = (float*)(ws + (16u<<20));                  // 8 MB
  float* bmax   = (float*)(ws + (24u<<20));                  // 32 KB
  float* csum   = (float*)(ws + (25u<<20));                  // 512 KB
  float* stateP = (float*)(ws + (28u<<20));                  // 4 MB
  unsigned short* sthi = (unsigned short*)(ws + (33u<<20));  // 2 MB
  unsigned short* stlo = (unsigned short*)(ws + (36u<<20));  // 2 MB

  k_proj       <<<1152, 256, 0, stream>>>(q, k, v, P, qfb, dshd, bmax, vtb);
  k_feat2      <<<512, 256, 0, stream>>>(dshd, bmax, kfb, kft, csum);
  k_state_build<<<dim3(64, NH), 64, 0, stream>>>(vtb, kft, stateP);
  k_state_scan <<<dim3(65, NH), 64, 0, stream>>>(stateP, sthi, stlo, csum);
  k_prime2     <<<512, 256, 0, stream>>>(qfb, kfb, csum);
  k_attn2      <<<dim3(64, NH), 128, 0, stream>>>(qfb, kfb, vtb, sthi, stlo, out);
}

// Round 12
// 58.503 us; speedup vs baseline: 1.3289x; 1.0442x over previous
//
#include <hip/hip_runtime.h>
#include <math.h>

// Problem constants (B=1, H=4, N=2048, D=64, M=256)
#define NH   4
#define SEQ  2048
#define DH   64
#define NF   256
#define ROWS (NH*SEQ)                // 8192
#define DN    0.35355339059327373f   // 64^-0.25
#define DIAGC 0.0625f                // 0.5*DN*DN
#define RATIO 0.0625f                // 1/sqrt(256)
#define EPSF  1e-4f

typedef __attribute__((ext_vector_type(8))) short bf8;
typedef __attribute__((ext_vector_type(4))) short bf4;
typedef __attribute__((ext_vector_type(4))) float f4;

static __device__ __forceinline__ unsigned short f2bf(float x) {
  union { float f; unsigned u; } v; v.f = x;
  unsigned r = v.u + 0x7FFF + ((v.u >> 16) & 1);
  return (unsigned short)(r >> 16);
}
static __device__ __forceinline__ float bf2f(unsigned short b) {
  union { unsigned u; float f; } v; v.u = ((unsigned)b) << 16;
  return v.f;
}

// ---- fused projection (q: full features; k: dsh-diag fp32 + rowmax) + V^T ----
// blocks 0..511: q tiles; 512..1023: k tiles; 1024..1151: V transpose.  (R11 verbatim)
__global__ __launch_bounds__(256) void k_proj(const float* __restrict__ q,
    const float* __restrict__ k, const float* __restrict__ v,
    const float* __restrict__ P,
    unsigned short* __restrict__ qfb, float* __restrict__ dshd,
    float* __restrict__ bmax, unsigned short* __restrict__ vtb) {
  __shared__ float lds[64*65];
  const int b = blockIdx.x;
  if (b >= 1024) {                       // ---- V transpose: 128 blocks ----
    const int cb = b - 1024;
    const int h = cb >> 5, n0 = (cb & 31) * 64;
    const int tid = threadIdx.x;
    for (int i = tid; i < 4096; i += 256) {
      int n = i >> 6, e = i & 63;
      lds[n*65 + e] = v[((size_t)h*SEQ + n0 + n)*DH + e];
    }
    __syncthreads();
    for (int i = tid; i < 4096; i += 256) {
      int e = i >> 6, n = i & 63;
      vtb[((size_t)h*DH + e)*SEQ + n0 + n] = f2bf(lds[n*65 + e]);
    }
    return;
  }
  const bool isq = b < 512;
  const int tile = isq ? b : b - 512;    // h*128 + t
  const int w = threadIdx.x >> 6, lane = threadIdx.x & 63;
  const int lr = lane & 15, g = lane >> 4;
  const float* x = (isq ? q : k) + (size_t)tile*16*DH;

  f4 a  = *(const f4*)(x + lr*DH + g*8);
  f4 bb = *(const f4*)(x + lr*DH + g*8 + 4);
  f4 c  = *(const f4*)(x + lr*DH + 32 + g*8);
  f4 d  = *(const f4*)(x + lr*DH + 32 + g*8 + 4);
  float ss = 0.f;
#pragma unroll
  for (int i = 0; i < 4; ++i) ss += a[i]*a[i] + bb[i]*bb[i] + c[i]*c[i] + d[i]*d[i];
  ss += __shfl_xor(ss, 16);
  ss += __shfl_xor(ss, 32);              // full sum(x^2) of row lr

  bf8 xh0, xh1, xl0, xl1;
#pragma unroll
  for (int i = 0; i < 4; ++i) {
    float v0 = DN*a[i], v1 = DN*bb[i], v2 = DN*c[i], v3 = DN*d[i];
    unsigned short h0 = f2bf(v0), h1 = f2bf(v1), h2 = f2bf(v2), h3 = f2bf(v3);
    xh0[i] = (short)h0; xh0[i+4] = (short)h1;
    xh1[i] = (short)h2; xh1[i+4] = (short)h3;
    xl0[i]   = (short)f2bf(v0 - bf2f(h0)); xl0[i+4] = (short)f2bf(v1 - bf2f(h1));
    xl1[i]   = (short)f2bf(v2 - bf2f(h2)); xl1[i+4] = (short)f2bf(v3 - bf2f(h3));
  }

  const int ct0 = w*4;
  f4 dsh[4];
#pragma unroll
  for (int cc = 0; cc < 4; ++cc) {
    const int ct = ct0 + cc;
    const float* prow = P + (ct*16 + lr)*DH + g*8;
    f4 p0 = *(const f4*)(prow);
    f4 p1 = *(const f4*)(prow + 4);
    f4 p2 = *(const f4*)(prow + 32);
    f4 p3 = *(const f4*)(prow + 36);
    bf8 bh0, bl0, bh1, bl1;
#pragma unroll
    for (int i = 0; i < 4; ++i) {
      unsigned short h0 = f2bf(p0[i]), h1 = f2bf(p1[i]);
      unsigned short h2 = f2bf(p2[i]), h3 = f2bf(p3[i]);
      bh0[i] = (short)h0; bh0[i+4] = (short)h1;
      bh1[i] = (short)h2; bh1[i+4] = (short)h3;
      bl0[i]   = (short)f2bf(p0[i] - bf2f(h0)); bl0[i+4] = (short)f2bf(p1[i] - bf2f(h1));
      bl1[i]   = (short)f2bf(p2[i] - bf2f(h2)); bl1[i+4] = (short)f2bf(p3[i] - bf2f(h3));
    }
    f4 acc = {0.f, 0.f, 0.f, 0.f};
    acc = __builtin_amdgcn_mfma_f32_16x16x32_bf16(xh0, bh0, acc, 0, 0, 0);
    acc = __builtin_amdgcn_mfma_f32_16x16x32_bf16(xh1, bh1, acc, 0, 0, 0);
    acc = __builtin_amdgcn_mfma_f32_16x16x32_bf16(xh0, bl0, acc, 0, 0, 0);
    acc = __builtin_amdgcn_mfma_f32_16x16x32_bf16(xh1, bl1, acc, 0, 0, 0);
    acc = __builtin_amdgcn_mfma_f32_16x16x32_bf16(xl0, bh0, acc, 0, 0, 0);
    acc = __builtin_amdgcn_mfma_f32_16x16x32_bf16(xl1, bh1, acc, 0, 0, 0);
    dsh[cc] = acc;
  }

  f4 mr;
#pragma unroll
  for (int r = 0; r < 4; ++r)
    mr[r] = fmaxf(fmaxf(dsh[0][r], dsh[1][r]), fmaxf(dsh[2][r], dsh[3][r]));
#pragma unroll
  for (int mk = 1; mk <= 8; mk <<= 1) {
#pragma unroll
    for (int r = 0; r < 4; ++r) mr[r] = fmaxf(mr[r], __shfl_xor(mr[r], mk));
  }
  if (lr == 0) {
#pragma unroll
    for (int r = 0; r < 4; ++r) lds[w*16 + 4*g + r] = mr[r];
  }
  __syncthreads();
  float rm[4], sr[4];
#pragma unroll
  for (int r = 0; r < 4; ++r) {
    rm[r] = fmaxf(fmaxf(lds[0*16 + 4*g + r], lds[1*16 + 4*g + r]),
                  fmaxf(lds[2*16 + 4*g + r], lds[3*16 + 4*g + r]));
    sr[r] = __shfl(ss, 4*g + r);
  }

  if (isq) {
    unsigned short* ob = qfb + (size_t)tile*16*NF;
#pragma unroll
    for (int cc = 0; cc < 4; ++cc) {
#pragma unroll
      for (int r = 0; r < 4; ++r)
        ob[(4*g + r)*NF + (ct0 + cc)*16 + lr] =
            f2bf(RATIO*(expf(dsh[cc][r] - (sr[r]*DIAGC + rm[r])) + EPSF));
    }
  } else {
    float* db = dshd + (size_t)tile*16*NF;
#pragma unroll
    for (int cc = 0; cc < 4; ++cc) {
#pragma unroll
      for (int r = 0; r < 4; ++r)
        db[(4*g + r)*NF + (ct0 + cc)*16 + lr] = dsh[cc][r] - sr[r]*DIAGC;
    }
    if (w == 0 && lr == 0) {
#pragma unroll
      for (int r = 0; r < 4; ++r) bmax[tile*16 + 4*g + r] = mr[r];
    }
  }
}

// ---- k_feat: gmax (inline) + exp -> kfb bf16 + kft (m-major) + tile sums ----
// (R11 verbatim)
__global__ __launch_bounds__(256) void k_feat2(const float* __restrict__ dshd,
    const float* __restrict__ bmax, unsigned short* __restrict__ kfb,
    unsigned short* __restrict__ kft, float* __restrict__ csum) {
  const int u = blockIdx.x, m = threadIdx.x;     // u: 0..511 = h*128 + t
  const int h = u >> 7, t = u & 127;
  __shared__ float red[256];
  float mx = -3.4e38f;
  for (int i = m; i < ROWS; i += 256) mx = fmaxf(mx, bmax[i]);
  red[m] = mx;
  __syncthreads();
  for (int s = 128; s > 0; s >>= 1) {
    if (m < s) red[m] = fmaxf(red[m], red[m+s]);
    __syncthreads();
  }
  const float gg = red[0];
  const float* db = dshd + (size_t)u*16*NF + m;
  unsigned short* ob = kfb + (size_t)u*16*NF + m;
  float run = 0.f;
  bf8 k0, k1;
#pragma unroll
  for (int r = 0; r < 16; ++r) {
    unsigned short bv = f2bf(RATIO*(expf(db[r*NF] - gg) + EPSF));
    ob[r*NF] = bv;
    if (r < 8) k0[r] = (short)bv; else k1[r-8] = (short)bv;
    run += bf2f(bv);
  }
  csum[(size_t)u*NF + m] = run;
  unsigned short* kt = kft + ((size_t)(h*NF + m))*SEQ + t*16;
  *(bf8*)kt = k0;
  *(bf8*)(kt + 8) = k1;
}

// ---- per-chunk state build: 1 wave/block, 256 blocks (R11 verbatim) ----
__global__ __launch_bounds__(64) void k_state_build(
    const unsigned short* __restrict__ vtb, const unsigned short* __restrict__ kft,
    float* __restrict__ stateP) {
  const int lane = threadIdx.x;
  const int lr = lane & 15, g = lane >> 4;
  const int c = blockIdx.x >> 2, mtg = blockIdx.x & 3;
  const int h = blockIdx.y;
  f4 acc[4][4];   // [et][mt]
#pragma unroll
  for (int et = 0; et < 4; ++et)
#pragma unroll
    for (int mt = 0; mt < 4; ++mt) acc[et][mt] = (f4){0.f,0.f,0.f,0.f};

#pragma unroll
  for (int ks = 0; ks < 4; ++ks) {
    const int j0 = c*128 + ks*32 + g*8;
    bf8 xv[4], ym[4];
#pragma unroll
    for (int et = 0; et < 4; ++et)
      xv[et] = *(const bf8*)(vtb + ((size_t)(h*DH + et*16 + lr))*SEQ + j0);
#pragma unroll
    for (int mt = 0; mt < 4; ++mt)
      ym[mt] = *(const bf8*)(kft + ((size_t)(h*NF + (4*mtg + mt)*16 + lr))*SEQ + j0);
#pragma unroll
    for (int et = 0; et < 4; ++et)
#pragma unroll
      for (int mt = 0; mt < 4; ++mt)
        acc[et][mt] = __builtin_amdgcn_mfma_f32_16x16x32_bf16(xv[et], ym[mt], acc[et][mt], 0, 0, 0);
  }
  float* sp = stateP + (size_t)(h*16 + c)*64*NF;
#pragma unroll
  for (int et = 0; et < 4; ++et)
#pragma unroll
    for (int mt = 0; mt < 4; ++mt)
#pragma unroll
      for (int r = 0; r < 4; ++r)
        sp[(size_t)(et*16 + 4*g + r)*NF + (4*mtg + mt)*16 + lr] = acc[et][mt][r];
}

// ---- exclusive cumsum of chunk states -> hi/lo + csum exclusive scan ----
// (R11 verbatim)
__global__ __launch_bounds__(64) void k_state_scan(const float* __restrict__ stateP,
    unsigned short* __restrict__ sthi, unsigned short* __restrict__ stlo,
    float* __restrict__ csum) {
  const int h = blockIdx.y;
  if (blockIdx.x == 64) {                // csum exclusive scan (in place)
    const int m0 = threadIdx.x * 4;
    f4 run = {0.f, 0.f, 0.f, 0.f};
#pragma unroll 4
    for (int c = 0; c < 128; ++c) {
      float* p = csum + ((size_t)(h*128 + c))*NF + m0;
      f4 x = *(const f4*)p;
      *(f4*)p = run;
      run += x;
    }
    return;
  }
  const int e = blockIdx.x;              // 0..63
  const int m0 = threadIdx.x * 4;
  f4 run = {0.f, 0.f, 0.f, 0.f};
  for (int c = 0; c < 16; ++c) {
    const size_t idx = (size_t)((h*16 + c)*64 + e)*NF + m0;
    unsigned short hi[4], lo[4];
#pragma unroll
    for (int i = 0; i < 4; ++i) {
      hi[i] = f2bf(run[i]);
      lo[i] = f2bf(run[i] - bf2f(hi[i]));
    }
    *(bf4*)(sthi + idx) = *(bf4*)hi;
    *(bf4*)(stlo + idx) = *(bf4*)lo;
    run += *(const f4*)(stateP + idx);
  }
}

// ---- chunked causal attention + fused q'-divide prologue (O(1) prefix) ----
// block = (h, chunk, quarter): t = c*8 + qt*2 + wid; 2 waves, 256 blocks total.
__global__ __launch_bounds__(128) void k_attn3(const unsigned short* __restrict__ qpb,
                                               const unsigned short* __restrict__ kfb,
                                               const unsigned short* __restrict__ vtb,
                                               const unsigned short* __restrict__ sthi,
                                               const unsigned short* __restrict__ stlo,
                                               const float* __restrict__ csum,
                                               float* __restrict__ out) {
  const int h = blockIdx.y;
  const int b = blockIdx.x;            // 0..63
  const int c = b >> 2, qt = b & 3;    // chunk 0..15, quarter 0..3
  const int tid = threadIdx.x;
  const int wid = tid >> 6, lane = tid & 63;
  const int t = c*8 + qt*2 + wid;      // this wave's row-tile (0..127)
  const int lr = lane & 15, g = lane >> 4;
  const int jc0 = c*8;
  const int nstage = qt*2 + 2;

  __shared__ __align__(16) char smem[26624];
  // Qs: [0,16384) 32 rows x 256 m bf16, XOR-swizzled
  char* Ks = smem + 16384;             // 8KB K-tile, XOR-swizzled
  char* Vs = smem + 24576;             // 2KB V-tile

  // ---- prime prologue: q' for this wave's 16 rows; lane owns 4 contiguous m ----
  {
    const int u = h*128 + t;
    f4 run = *(const f4*)(csum + (size_t)u*NF + lane*4);   // exclusive prefix
    const unsigned short* kfp = kfb + ((size_t)(h*SEQ + t*16))*NF + lane*4;
    const unsigned short* qfp = qpb + ((size_t)(h*SEQ + t*16))*NF + lane*4;
#pragma unroll
    for (int r = 0; r < 16; ++r) {
      bf4 kv = *(const bf4*)(kfp + (size_t)r*NF);
      bf4 qv = *(const bf4*)(qfp + (size_t)r*NF);
      unsigned short qp[4];
#pragma unroll
      for (int i = 0; i < 4; ++i) {
        run[i] += bf2f((unsigned short)kv[i]);
        qp[i] = f2bf(bf2f((unsigned short)qv[i]) / run[i]);
      }
      const int rloc = wid*16 + r;
      const int byte = (rloc*512 + lane*8) ^ ((rloc & 7) << 4);
      *(bf4*)(smem + byte) = *(bf4*)qp;
    }
  }
  __syncthreads();

  // Q' A-fragments from swizzled LDS (wave reads its own rows)
  bf8 qf[8];
  {
    const int rloc = wid*16 + lr;
#pragma unroll
    for (int kb = 0; kb < 8; ++kb) {
      const int byte = (rloc*512 + g*16 + kb*64) ^ ((rloc & 7) << 4);
      qf[kb] = *(const bf8*)(smem + byte);
    }
  }

  const char* kTile = (const char*)(kfb + (size_t)h*SEQ*NF);
  const char* vTile = (const char*)(vtb + (size_t)h*DH*SEQ);

  // staging offsets: 128 threads x 64B = 8KB K-tile; 128 x 16B = 2KB V-tile
  const int ko0 = wid*4096 +    0 + lane*16;
  const int ko1 = wid*4096 + 1024 + lane*16;
  const int ko2 = wid*4096 + 2048 + lane*16;
  const int ko3 = wid*4096 + 3072 + lane*16;
  const int kw0 = ko0 ^ (((ko0 >> 9) & 7) << 4);
  const int kw1 = ko1 ^ (((ko1 >> 9) & 7) << 4);
  const int kw2 = ko2 ^ (((ko2 >> 9) & 7) << 4);
  const int kw3 = ko3 ^ (((ko3 >> 9) & 7) << 4);
  const int vo = tid*16;               // V LDS byte offset
  const int ve = vo >> 5;              // e row (0..63)
  const int vn = vo & 31;              // byte within 32B n-row

  f4 sk0, sk1, sk2, sk3, sv;
  {  // issue staging loads for first j-tile (fly under inter-GEMM)
    const char* kt = kTile + (size_t)jc0*8192;
    sk0 = *(const f4*)(kt + ko0);
    sk1 = *(const f4*)(kt + ko1);
    sk2 = *(const f4*)(kt + ko2);
    sk3 = *(const f4*)(kt + ko3);
    sv  = *(const f4*)(vTile + (size_t)ve*4096 + (size_t)jc0*32 + vn);
  }

  // ---- inter-chunk: O = q' x cumstate (hi/lo split) ----
  f4 o0 = {0,0,0,0}, o1 = {0,0,0,0}, o2 = {0,0,0,0}, o3 = {0,0,0,0};
  {
    const unsigned short* SH = sthi + ((size_t)((h*16 + c)*64 + lr))*NF + g*8;
    const unsigned short* SL = stlo + ((size_t)((h*16 + c)*64 + lr))*NF + g*8;
#pragma unroll
    for (int ks = 0; ks < 8; ++ks) {
#pragma unroll
      for (int et = 0; et < 4; ++et) {
        bf8 bh = *(const bf8*)(SH + et*16*NF + ks*32);
        bf8 bl = *(const bf8*)(SL + et*16*NF + ks*32);
        f4 acc = (et == 0) ? o0 : (et == 1) ? o1 : (et == 2) ? o2 : o3;
        acc = __builtin_amdgcn_mfma_f32_16x16x32_bf16(qf[ks], bh, acc, 0, 0, 0);
        acc = __builtin_amdgcn_mfma_f32_16x16x32_bf16(qf[ks], bl, acc, 0, 0, 0);
        if (et == 0) o0 = acc; else if (et == 1) o1 = acc; else if (et == 2) o2 = acc; else o3 = acc;
      }
    }
  }

  // ---- intra-chunk causal sweep over staged K/V tiles ----
  for (int jj = 0; jj < nstage; ++jj) {
    const int j = jc0 + jj;
    *(f4*)(Ks + kw0) = sk0;
    *(f4*)(Ks + kw1) = sk1;
    *(f4*)(Ks + kw2) = sk2;
    *(f4*)(Ks + kw3) = sk3;
    *(f4*)(Vs + vo) = sv;
    __syncthreads();
    if (jj + 1 < nstage) {
      const char* kt = kTile + (size_t)(j+1)*8192;
      sk0 = *(const f4*)(kt + ko0);
      sk1 = *(const f4*)(kt + ko1);
      sk2 = *(const f4*)(kt + ko2);
      sk3 = *(const f4*)(kt + ko3);
      sv  = *(const f4*)(vTile + (size_t)ve*4096 + (size_t)(j+1)*32 + vn);
    }
    if (j <= t) {
      bf8 kcs[8];
#pragma unroll
      for (int kb = 0; kb < 8; ++kb) {
        int off = (lr*512 + kb*64 + g*16) ^ ((lr & 7) << 4);
        kcs[kb] = *(const bf8*)(Ks + off);
      }
      f4 st = {0,0,0,0};
#pragma unroll
      for (int kb = 0; kb < 8; ++kb)
        st = __builtin_amdgcn_mfma_f32_16x16x32_bf16(kcs[kb], qf[kb], st, 0, 0, 0);
      if (j == t) {
#pragma unroll
        for (int rr = 0; rr < 4; ++rr) if (g*4 + rr > lr) st[rr] = 0.f;
      }
      bf8 sb = { (short)f2bf(st[0]), (short)f2bf(st[1]), (short)f2bf(st[2]), (short)f2bf(st[3]),
                 (short)0, (short)0, (short)0, (short)0 };
#pragma unroll
      for (int eb = 0; eb < 4; ++eb) {
        bf4 v4 = *(const bf4*)(Vs + (eb*16 + lr)*32 + g*8);
        bf8 vf = { v4[0], v4[1], v4[2], v4[3], (short)0, (short)0, (short)0, (short)0 };
        f4 acc = (eb == 0) ? o0 : (eb == 1) ? o1 : (eb == 2) ? o2 : o3;
        acc = __builtin_amdgcn_mfma_f32_16x16x32_bf16(sb, vf, acc, 0, 0, 0);
        if (eb == 0) o0 = acc; else if (eb == 1) o1 = acc; else if (eb == 2) o2 = acc; else o3 = acc;
      }
    }
    __syncthreads();
  }

  float* ob = out + ((size_t)(h*SEQ + t*16))*DH;
#pragma unroll
  for (int rr = 0; rr < 4; ++rr) {
    ob[(size_t)(4*g + rr)*DH +  0 + lr] = o0[rr];
    ob[(size_t)(4*g + rr)*DH + 16 + lr] = o1[rr];
    ob[(size_t)(4*g + rr)*DH + 32 + lr] = o2[rr];
    ob[(size_t)(4*g + rr)*DH + 48 + lr] = o3[rr];
  }
}

extern "C" void kernel_launch(void* const* d_in, const int* in_sizes, int n_in,
                              void* d_out, int out_size, void* d_ws, size_t ws_size,
                              hipStream_t stream) {
  const float* q = (const float*)d_in[0];
  const float* k = (const float*)d_in[1];
  const float* v = (const float*)d_in[2];
  const float* P = (const float*)d_in[3];
  float* out = (float*)d_out;

  char* ws = (char*)d_ws;                                    // 256 MiB available
  unsigned short* qfb  = (unsigned short*)(ws);              // 4 MB (q_feat, read-only after proj)
  unsigned short* kfb  = (unsigned short*)(ws + (4u<<20));   // 4 MB
  unsigned short* vtb  = (unsigned short*)(ws + (8u<<20));   // 1 MB
  unsigned short* kft  = (unsigned short*)(ws + (12u<<20));  // 4 MB (m-major kf)
  float* dshd   = (float*)(ws + (16u<<20));                  // 8 MB
  float* bmax   = (float*)(ws + (24u<<20));                  // 32 KB
  float* csum   = (float*)(ws + (25u<<20));                  // 512 KB
  float* stateP = (float*)(ws + (28u<<20));                  // 4 MB
  unsigned short* sthi = (unsigned short*)(ws + (33u<<20));  // 2 MB
  unsigned short* stlo = (unsigned short*)(ws + (36u<<20));  // 2 MB

  k_proj       <<<1152, 256, 0, stream>>>(q, k, v, P, qfb, dshd, bmax, vtb);
  k_feat2      <<<512, 256, 0, stream>>>(dshd, bmax, kfb, kft, csum);
  k_state_build<<<dim3(64, NH), 64, 0, stream>>>(vtb, kft, stateP);
  k_state_scan <<<dim3(65, NH), 64, 0, stream>>>(stateP, sthi, stlo, csum);
  k_attn3      <<<dim3(64, NH), 128, 0, stream>>>(qfb, kfb, vtb, sthi, stlo, csum, out);
}

// Round 13
// 57.881 us; speedup vs baseline: 1.3432x; 1.0107x over previous
//
#include <hip/hip_runtime.h>
#include <math.h>

// Problem constants (B=1, H=4, N=2048, D=64, M=256)
#define NH   4
#define SEQ  2048
#define DH   64
#define NF   256
#define ROWS (NH*SEQ)                // 8192
#define DN    0.35355339059327373f   // 64^-0.25
#define DIAGC 0.0625f                // 0.5*DN*DN
#define RATIO 0.0625f                // 1/sqrt(256)
#define EPSF  1e-4f

typedef __attribute__((ext_vector_type(8))) short bf8;
typedef __attribute__((ext_vector_type(4))) short bf4;
typedef __attribute__((ext_vector_type(4))) float f4;

static __device__ __forceinline__ unsigned short f2bf(float x) {
  union { float f; unsigned u; } v; v.f = x;
  unsigned r = v.u + 0x7FFF + ((v.u >> 16) & 1);
  return (unsigned short)(r >> 16);
}
static __device__ __forceinline__ float bf2f(unsigned short b) {
  union { unsigned u; float f; } v; v.u = ((unsigned)b) << 16;
  return v.f;
}

// ---- fused projection (q: full features; k: dsh-diag fp32 + rowmax) + V^T ----
// blocks 0..511: q tiles; 512..1023: k tiles; 1024..1151: V transpose. (R12 verbatim)
__global__ __launch_bounds__(256) void k_proj(const float* __restrict__ q,
    const float* __restrict__ k, const float* __restrict__ v,
    const float* __restrict__ P,
    unsigned short* __restrict__ qfb, float* __restrict__ dshd,
    float* __restrict__ bmax, unsigned short* __restrict__ vtb) {
  __shared__ float lds[64*65];
  const int b = blockIdx.x;
  if (b >= 1024) {                       // ---- V transpose: 128 blocks ----
    const int cb = b - 1024;
    const int h = cb >> 5, n0 = (cb & 31) * 64;
    const int tid = threadIdx.x;
    for (int i = tid; i < 4096; i += 256) {
      int n = i >> 6, e = i & 63;
      lds[n*65 + e] = v[((size_t)h*SEQ + n0 + n)*DH + e];
    }
    __syncthreads();
    for (int i = tid; i < 4096; i += 256) {
      int e = i >> 6, n = i & 63;
      vtb[((size_t)h*DH + e)*SEQ + n0 + n] = f2bf(lds[n*65 + e]);
    }
    return;
  }
  const bool isq = b < 512;
  const int tile = isq ? b : b - 512;    // h*128 + t
  const int w = threadIdx.x >> 6, lane = threadIdx.x & 63;
  const int lr = lane & 15, g = lane >> 4;
  const float* x = (isq ? q : k) + (size_t)tile*16*DH;

  f4 a  = *(const f4*)(x + lr*DH + g*8);
  f4 bb = *(const f4*)(x + lr*DH + g*8 + 4);
  f4 c  = *(const f4*)(x + lr*DH + 32 + g*8);
  f4 d  = *(const f4*)(x + lr*DH + 32 + g*8 + 4);
  float ss = 0.f;
#pragma unroll
  for (int i = 0; i < 4; ++i) ss += a[i]*a[i] + bb[i]*bb[i] + c[i]*c[i] + d[i]*d[i];
  ss += __shfl_xor(ss, 16);
  ss += __shfl_xor(ss, 32);              // full sum(x^2) of row lr

  bf8 xh0, xh1, xl0, xl1;
#pragma unroll
  for (int i = 0; i < 4; ++i) {
    float v0 = DN*a[i], v1 = DN*bb[i], v2 = DN*c[i], v3 = DN*d[i];
    unsigned short h0 = f2bf(v0), h1 = f2bf(v1), h2 = f2bf(v2), h3 = f2bf(v3);
    xh0[i] = (short)h0; xh0[i+4] = (short)h1;
    xh1[i] = (short)h2; xh1[i+4] = (short)h3;
    xl0[i]   = (short)f2bf(v0 - bf2f(h0)); xl0[i+4] = (short)f2bf(v1 - bf2f(h1));
    xl1[i]   = (short)f2bf(v2 - bf2f(h2)); xl1[i+4] = (short)f2bf(v3 - bf2f(h3));
  }

  const int ct0 = w*4;
  f4 dsh[4];
#pragma unroll
  for (int cc = 0; cc < 4; ++cc) {
    const int ct = ct0 + cc;
    const float* prow = P + (ct*16 + lr)*DH + g*8;
    f4 p0 = *(const f4*)(prow);
    f4 p1 = *(const f4*)(prow + 4);
    f4 p2 = *(const f4*)(prow + 32);
    f4 p3 = *(const f4*)(prow + 36);
    bf8 bh0, bl0, bh1, bl1;
#pragma unroll
    for (int i = 0; i < 4; ++i) {
      unsigned short h0 = f2bf(p0[i]), h1 = f2bf(p1[i]);
      unsigned short h2 = f2bf(p2[i]), h3 = f2bf(p3[i]);
      bh0[i] = (short)h0; bh0[i+4] = (short)h1;
      bh1[i] = (short)h2; bh1[i+4] = (short)h3;
      bl0[i]   = (short)f2bf(p0[i] - bf2f(h0)); bl0[i+4] = (short)f2bf(p1[i] - bf2f(h1));
      bl1[i]   = (short)f2bf(p2[i] - bf2f(h2)); bl1[i+4] = (short)f2bf(p3[i] - bf2f(h3));
    }
    f4 acc = {0.f, 0.f, 0.f, 0.f};
    acc = __builtin_amdgcn_mfma_f32_16x16x32_bf16(xh0, bh0, acc, 0, 0, 0);
    acc = __builtin_amdgcn_mfma_f32_16x16x32_bf16(xh1, bh1, acc, 0, 0, 0);
    acc = __builtin_amdgcn_mfma_f32_16x16x32_bf16(xh0, bl0, acc, 0, 0, 0);
    acc = __builtin_amdgcn_mfma_f32_16x16x32_bf16(xh1, bl1, acc, 0, 0, 0);
    acc = __builtin_amdgcn_mfma_f32_16x16x32_bf16(xl0, bh0, acc, 0, 0, 0);
    acc = __builtin_amdgcn_mfma_f32_16x16x32_bf16(xl1, bh1, acc, 0, 0, 0);
    dsh[cc] = acc;
  }

  f4 mr;
#pragma unroll
  for (int r = 0; r < 4; ++r)
    mr[r] = fmaxf(fmaxf(dsh[0][r], dsh[1][r]), fmaxf(dsh[2][r], dsh[3][r]));
#pragma unroll
  for (int mk = 1; mk <= 8; mk <<= 1) {
#pragma unroll
    for (int r = 0; r < 4; ++r) mr[r] = fmaxf(mr[r], __shfl_xor(mr[r], mk));
  }
  if (lr == 0) {
#pragma unroll
    for (int r = 0; r < 4; ++r) lds[w*16 + 4*g + r] = mr[r];
  }
  __syncthreads();
  float rm[4], sr[4];
#pragma unroll
  for (int r = 0; r < 4; ++r) {
    rm[r] = fmaxf(fmaxf(lds[0*16 + 4*g + r], lds[1*16 + 4*g + r]),
                  fmaxf(lds[2*16 + 4*g + r], lds[3*16 + 4*g + r]));
    sr[r] = __shfl(ss, 4*g + r);
  }

  if (isq) {
    unsigned short* ob = qfb + (size_t)tile*16*NF;
#pragma unroll
    for (int cc = 0; cc < 4; ++cc) {
#pragma unroll
      for (int r = 0; r < 4; ++r)
        ob[(4*g + r)*NF + (ct0 + cc)*16 + lr] =
            f2bf(RATIO*(expf(dsh[cc][r] - (sr[r]*DIAGC + rm[r])) + EPSF));
    }
  } else {
    float* db = dshd + (size_t)tile*16*NF;
#pragma unroll
    for (int cc = 0; cc < 4; ++cc) {
#pragma unroll
      for (int r = 0; r < 4; ++r)
        db[(4*g + r)*NF + (ct0 + cc)*16 + lr] = dsh[cc][r] - sr[r]*DIAGC;
    }
    if (w == 0 && lr == 0) {
#pragma unroll
      for (int r = 0; r < 4; ++r) bmax[tile*16 + 4*g + r] = mr[r];
    }
  }
}

// ---- k_feat: gmax (inline) + exp -> kfb bf16 + kft (m-major) + tile sums ----
// (R12 verbatim)
__global__ __launch_bounds__(256) void k_feat2(const float* __restrict__ dshd,
    const float* __restrict__ bmax, unsigned short* __restrict__ kfb,
    unsigned short* __restrict__ kft, float* __restrict__ csum) {
  const int u = blockIdx.x, m = threadIdx.x;     // u: 0..511 = h*128 + t
  const int h = u >> 7, t = u & 127;
  __shared__ float red[256];
  float mx = -3.4e38f;
  for (int i = m; i < ROWS; i += 256) mx = fmaxf(mx, bmax[i]);
  red[m] = mx;
  __syncthreads();
  for (int s = 128; s > 0; s >>= 1) {
    if (m < s) red[m] = fmaxf(red[m], red[m+s]);
    __syncthreads();
  }
  const float gg = red[0];
  const float* db = dshd + (size_t)u*16*NF + m;
  unsigned short* ob = kfb + (size_t)u*16*NF + m;
  float run = 0.f;
  bf8 k0, k1;
#pragma unroll
  for (int r = 0; r < 16; ++r) {
    unsigned short bv = f2bf(RATIO*(expf(db[r*NF] - gg) + EPSF));
    ob[r*NF] = bv;
    if (r < 8) k0[r] = (short)bv; else k1[r-8] = (short)bv;
    run += bf2f(bv);
  }
  csum[(size_t)u*NF + m] = run;
  unsigned short* kt = kft + ((size_t)(h*NF + m))*SEQ + t*16;
  *(bf8*)kt = k0;
  *(bf8*)(kt + 8) = k1;
}

// ---- fused state build + exclusive cumsum -> hi/lo  +  csum scan ----
// blocks 0..255: wave-unit (h, et, mt) walks 16 chunks (build+scan in one pass).
// blocks 256..259: csum exclusive scan for head (b-256).
__global__ __launch_bounds__(64) void k_state(
    const unsigned short* __restrict__ vtb, const unsigned short* __restrict__ kft,
    unsigned short* __restrict__ sthi, unsigned short* __restrict__ stlo,
    float* __restrict__ csum) {
  const int bx = blockIdx.x;
  if (bx >= 256) {                       // ---- csum exclusive scan (in place) ----
    const int h = bx - 256;
    const int m0 = threadIdx.x * 4;
    f4 run = {0.f, 0.f, 0.f, 0.f};
#pragma unroll 4
    for (int c = 0; c < 128; ++c) {
      float* p = csum + ((size_t)(h*128 + c))*NF + m0;
      f4 x = *(const f4*)p;
      *(f4*)p = run;
      run += x;
    }
    return;
  }
  const int lane = threadIdx.x;          // 0..63
  const int lr = lane & 15, g = lane >> 4;
  const int h = bx >> 6, et = (bx >> 4) & 3, mt = bx & 15;

  const unsigned short* vb = vtb + ((size_t)(h*DH + et*16 + lr))*SEQ;
  const unsigned short* kb = kft + ((size_t)(h*NF + mt*16 + lr))*SEQ;

  f4 cum = {0.f, 0.f, 0.f, 0.f};
  for (int c = 0; c < 16; ++c) {
    // write EXCLUSIVE cumulative state (hi/lo) for chunk c
    const size_t base = ((size_t)((h*16 + c)*64 + et*16 + 4*g))*NF + mt*16 + lr;
#pragma unroll
    for (int r = 0; r < 4; ++r) {
      unsigned short hi = f2bf(cum[r]);
      sthi[base + (size_t)r*NF] = hi;
      stlo[base + (size_t)r*NF] = f2bf(cum[r] - bf2f(hi));
    }
    // accumulate chunk c
#pragma unroll
    for (int ks = 0; ks < 4; ++ks) {
      const int j0 = c*128 + ks*32 + g*8;
      bf8 xv = *(const bf8*)(vb + j0);
      bf8 ym = *(const bf8*)(kb + j0);
      cum = __builtin_amdgcn_mfma_f32_16x16x32_bf16(xv, ym, cum, 0, 0, 0);
    }
  }
}

// ---- chunked causal attention + fused q'-divide prologue (O(1) prefix) ----
// (R12 verbatim)
__global__ __launch_bounds__(128) void k_attn3(const unsigned short* __restrict__ qpb,
                                               const unsigned short* __restrict__ kfb,
                                               const unsigned short* __restrict__ vtb,
                                               const unsigned short* __restrict__ sthi,
                                               const unsigned short* __restrict__ stlo,
                                               const float* __restrict__ csum,
                                               float* __restrict__ out) {
  const int h = blockIdx.y;
  const int b = blockIdx.x;            // 0..63
  const int c = b >> 2, qt = b & 3;    // chunk 0..15, quarter 0..3
  const int tid = threadIdx.x;
  const int wid = tid >> 6, lane = tid & 63;
  const int t = c*8 + qt*2 + wid;      // this wave's row-tile (0..127)
  const int lr = lane & 15, g = lane >> 4;
  const int jc0 = c*8;
  const int nstage = qt*2 + 2;

  __shared__ __align__(16) char smem[26624];
  // Qs: [0,16384) 32 rows x 256 m bf16, XOR-swizzled
  char* Ks = smem + 16384;             // 8KB K-tile, XOR-swizzled
  char* Vs = smem + 24576;             // 2KB V-tile

  // ---- prime prologue: q' for this wave's 16 rows; lane owns 4 contiguous m ----
  {
    const int u = h*128 + t;
    f4 run = *(const f4*)(csum + (size_t)u*NF + lane*4);   // exclusive prefix
    const unsigned short* kfp = kfb + ((size_t)(h*SEQ + t*16))*NF + lane*4;
    const unsigned short* qfp = qpb + ((size_t)(h*SEQ + t*16))*NF + lane*4;
#pragma unroll
    for (int r = 0; r < 16; ++r) {
      bf4 kv = *(const bf4*)(kfp + (size_t)r*NF);
      bf4 qv = *(const bf4*)(qfp + (size_t)r*NF);
      unsigned short qp[4];
#pragma unroll
      for (int i = 0; i < 4; ++i) {
        run[i] += bf2f((unsigned short)kv[i]);
        qp[i] = f2bf(bf2f((unsigned short)qv[i]) / run[i]);
      }
      const int rloc = wid*16 + r;
      const int byte = (rloc*512 + lane*8) ^ ((rloc & 7) << 4);
      *(bf4*)(smem + byte) = *(bf4*)qp;
    }
  }
  __syncthreads();

  // Q' A-fragments from swizzled LDS (wave reads its own rows)
  bf8 qf[8];
  {
    const int rloc = wid*16 + lr;
#pragma unroll
    for (int kb = 0; kb < 8; ++kb) {
      const int byte = (rloc*512 + g*16 + kb*64) ^ ((rloc & 7) << 4);
      qf[kb] = *(const bf8*)(smem + byte);
    }
  }

  const char* kTile = (const char*)(kfb + (size_t)h*SEQ*NF);
  const char* vTile = (const char*)(vtb + (size_t)h*DH*SEQ);

  // staging offsets: 128 threads x 64B = 8KB K-tile; 128 x 16B = 2KB V-tile
  const int ko0 = wid*4096 +    0 + lane*16;
  const int ko1 = wid*4096 + 1024 + lane*16;
  const int ko2 = wid*4096 + 2048 + lane*16;
  const int ko3 = wid*4096 + 3072 + lane*16;
  const int kw0 = ko0 ^ (((ko0 >> 9) & 7) << 4);
  const int kw1 = ko1 ^ (((ko1 >> 9) & 7) << 4);
  const int kw2 = ko2 ^ (((ko2 >> 9) & 7) << 4);
  const int kw3 = ko3 ^ (((ko3 >> 9) & 7) << 4);
  const int vo = tid*16;               // V LDS byte offset
  const int ve = vo >> 5;              // e row (0..63)
  const int vn = vo & 31;              // byte within 32B n-row

  f4 sk0, sk1, sk2, sk3, sv;
  {  // issue staging loads for first j-tile (fly under inter-GEMM)
    const char* kt = kTile + (size_t)jc0*8192;
    sk0 = *(const f4*)(kt + ko0);
    sk1 = *(const f4*)(kt + ko1);
    sk2 = *(const f4*)(kt + ko2);
    sk3 = *(const f4*)(kt + ko3);
    sv  = *(const f4*)(vTile + (size_t)ve*4096 + (size_t)jc0*32 + vn);
  }

  // ---- inter-chunk: O = q' x cumstate (hi/lo split) ----
  f4 o0 = {0,0,0,0}, o1 = {0,0,0,0}, o2 = {0,0,0,0}, o3 = {0,0,0,0};
  {
    const unsigned short* SH = sthi + ((size_t)((h*16 + c)*64 + lr))*NF + g*8;
    const unsigned short* SL = stlo + ((size_t)((h*16 + c)*64 + lr))*NF + g*8;
#pragma unroll
    for (int ks = 0; ks < 8; ++ks) {
#pragma unroll
      for (int et = 0; et < 4; ++et) {
        bf8 bh = *(const bf8*)(SH + et*16*NF + ks*32);
        bf8 bl = *(const bf8*)(SL + et*16*NF + ks*32);
        f4 acc = (et == 0) ? o0 : (et == 1) ? o1 : (et == 2) ? o2 : o3;
        acc = __builtin_amdgcn_mfma_f32_16x16x32_bf16(qf[ks], bh, acc, 0, 0, 0);
        acc = __builtin_amdgcn_mfma_f32_16x16x32_bf16(qf[ks], bl, acc, 0, 0, 0);
        if (et == 0) o0 = acc; else if (et == 1) o1 = acc; else if (et == 2) o2 = acc; else o3 = acc;
      }
    }
  }

  // ---- intra-chunk causal sweep over staged K/V tiles ----
  for (int jj = 0; jj < nstage; ++jj) {
    const int j = jc0 + jj;
    *(f4*)(Ks + kw0) = sk0;
    *(f4*)(Ks + kw1) = sk1;
    *(f4*)(Ks + kw2) = sk2;
    *(f4*)(Ks + kw3) = sk3;
    *(f4*)(Vs + vo) = sv;
    __syncthreads();
    if (jj + 1 < nstage) {
      const char* kt = kTile + (size_t)(j+1)*8192;
      sk0 = *(const f4*)(kt + ko0);
      sk1 = *(const f4*)(kt + ko1);
      sk2 = *(const f4*)(kt + ko2);
      sk3 = *(const f4*)(kt + ko3);
      sv  = *(const f4*)(vTile + (size_t)ve*4096 + (size_t)(j+1)*32 + vn);
    }
    if (j <= t) {
      bf8 kcs[8];
#pragma unroll
      for (int kb = 0; kb < 8; ++kb) {
        int off = (lr*512 + kb*64 + g*16) ^ ((lr & 7) << 4);
        kcs[kb] = *(const bf8*)(Ks + off);
      }
      f4 st = {0,0,0,0};
#pragma unroll
      for (int kb = 0; kb < 8; ++kb)
        st = __builtin_amdgcn_mfma_f32_16x16x32_bf16(kcs[kb], qf[kb], st, 0, 0, 0);
      if (j == t) {
#pragma unroll
        for (int rr = 0; rr < 4; ++rr) if (g*4 + rr > lr) st[rr] = 0.f;
      }
      bf8 sb = { (short)f2bf(st[0]), (short)f2bf(st[1]), (short)f2bf(st[2]), (short)f2bf(st[3]),
                 (short)0, (short)0, (short)0, (short)0 };
#pragma unroll
      for (int eb = 0; eb < 4; ++eb) {
        bf4 v4 = *(const bf4*)(Vs + (eb*16 + lr)*32 + g*8);
        bf8 vf = { v4[0], v4[1], v4[2], v4[3], (short)0, (short)0, (short)0, (short)0 };
        f4 acc = (eb == 0) ? o0 : (eb == 1) ? o1 : (eb == 2) ? o2 : o3;
        acc = __builtin_amdgcn_mfma_f32_16x16x32_bf16(sb, vf, acc, 0, 0, 0);
        if (eb == 0) o0 = acc; else if (eb == 1) o1 = acc; else if (eb == 2) o2 = acc; else o3 = acc;
      }
    }
    __syncthreads();
  }

  float* ob = out + ((size_t)(h*SEQ + t*16))*DH;
#pragma unroll
  for (int rr = 0; rr < 4; ++rr) {
    ob[(size_t)(4*g + rr)*DH +  0 + lr] = o0[rr];
    ob[(size_t)(4*g + rr)*DH + 16 + lr] = o1[rr];
    ob[(size_t)(4*g + rr)*DH + 32 + lr] = o2[rr];
    ob[(size_t)(4*g + rr)*DH + 48 + lr] = o3[rr];
  }
}

extern "C" void kernel_launch(void* const* d_in, const int* in_sizes, int n_in,
                              void* d_out, int out_size, void* d_ws, size_t ws_size,
                              hipStream_t stream) {
  const float* q = (const float*)d_in[0];
  const float* k = (const float*)d_in[1];
  const float* v = (const float*)d_in[2];
  const float* P = (const float*)d_in[3];
  float* out = (float*)d_out;

  char* ws = (char*)d_ws;                                    // 256 MiB available
  unsigned short* qfb  = (unsigned short*)(ws);              // 4 MB (read-only after proj)
  unsigned short* kfb  = (unsigned short*)(ws + (4u<<20));   // 4 MB
  unsigned short* vtb  = (unsigned short*)(ws + (8u<<20));   // 1 MB
  unsigned short* kft  = (unsigned short*)(ws + (12u<<20));  // 4 MB (m-major kf)
  float* dshd   = (float*)(ws + (16u<<20));                  // 8 MB
  float* bmax   = (float*)(ws + (24u<<20));                  // 32 KB
  float* csum   = (float*)(ws + (25u<<20));                  // 512 KB
  unsigned short* sthi = (unsigned short*)(ws + (33u<<20));  // 2 MB
  unsigned short* stlo = (unsigned short*)(ws + (36u<<20));  // 2 MB

  k_proj  <<<1152, 256, 0, stream>>>(q, k, v, P, qfb, dshd, bmax, vtb);
  k_feat2 <<<512, 256, 0, stream>>>(dshd, bmax, kfb, kft, csum);
  k_state <<<260, 64, 0, stream>>>(vtb, kft, sthi, stlo, csum);
  k_attn3 <<<dim3(64, NH), 128, 0, stream>>>(qfb, kfb, vtb, sthi, stlo, csum, out);
}

// Round 14
// 54.335 us; speedup vs baseline: 1.4309x; 1.0653x over previous
//
#include <hip/hip_runtime.h>
#include <math.h>

// Problem constants (B=1, H=4, N=2048, D=64, M=256)
#define NH   4
#define SEQ  2048
#define DH   64
#define NF   256
#define ROWS (NH*SEQ)                // 8192
#define DN    0.35355339059327373f   // 64^-0.25
#define DIAGC 0.0625f                // 0.5*DN*DN
#define RATIO 0.0625f                // 1/sqrt(256)
#define EPSF  1e-4f

typedef __attribute__((ext_vector_type(8))) short bf8;
typedef __attribute__((ext_vector_type(4))) short bf4;
typedef __attribute__((ext_vector_type(4))) float f4;

static __device__ __forceinline__ unsigned short f2bf(float x) {
  union { float f; unsigned u; } v; v.f = x;
  unsigned r = v.u + 0x7FFF + ((v.u >> 16) & 1);
  return (unsigned short)(r >> 16);
}
static __device__ __forceinline__ float bf2f(unsigned short b) {
  union { unsigned u; float f; } v; v.u = ((unsigned)b) << 16;
  return v.f;
}

// ---- fused projection (q: full features; k: dsh-diag fp32 + tile max) + V^T ----
// blocks 0..511: q tiles; 512..1023: k tiles; 1024..1151: V transpose.
__global__ __launch_bounds__(256) void k_proj(const float* __restrict__ q,
    const float* __restrict__ k, const float* __restrict__ v,
    const float* __restrict__ P,
    unsigned short* __restrict__ qfb, float* __restrict__ dshd,
    float* __restrict__ bmax, unsigned short* __restrict__ vtb) {
  __shared__ float lds[64*65];
  const int b = blockIdx.x;
  if (b >= 1024) {                       // ---- V transpose: 128 blocks ----
    const int cb = b - 1024;
    const int h = cb >> 5, n0 = (cb & 31) * 64;
    const int tid = threadIdx.x;
    for (int i = tid; i < 4096; i += 256) {
      int n = i >> 6, e = i & 63;
      lds[n*65 + e] = v[((size_t)h*SEQ + n0 + n)*DH + e];
    }
    __syncthreads();
    for (int i = tid; i < 4096; i += 256) {
      int e = i >> 6, n = i & 63;
      vtb[((size_t)h*DH + e)*SEQ + n0 + n] = f2bf(lds[n*65 + e]);
    }
    return;
  }
  const bool isq = b < 512;
  const int tile = isq ? b : b - 512;    // h*128 + t
  const int w = threadIdx.x >> 6, lane = threadIdx.x & 63;
  const int lr = lane & 15, g = lane >> 4;
  const float* x = (isq ? q : k) + (size_t)tile*16*DH;

  f4 a  = *(const f4*)(x + lr*DH + g*8);
  f4 bb = *(const f4*)(x + lr*DH + g*8 + 4);
  f4 c  = *(const f4*)(x + lr*DH + 32 + g*8);
  f4 d  = *(const f4*)(x + lr*DH + 32 + g*8 + 4);
  float ss = 0.f;
#pragma unroll
  for (int i = 0; i < 4; ++i) ss += a[i]*a[i] + bb[i]*bb[i] + c[i]*c[i] + d[i]*d[i];
  ss += __shfl_xor(ss, 16);
  ss += __shfl_xor(ss, 32);              // full sum(x^2) of row lr

  bf8 xh0, xh1, xl0, xl1;
#pragma unroll
  for (int i = 0; i < 4; ++i) {
    float v0 = DN*a[i], v1 = DN*bb[i], v2 = DN*c[i], v3 = DN*d[i];
    unsigned short h0 = f2bf(v0), h1 = f2bf(v1), h2 = f2bf(v2), h3 = f2bf(v3);
    xh0[i] = (short)h0; xh0[i+4] = (short)h1;
    xh1[i] = (short)h2; xh1[i+4] = (short)h3;
    xl0[i]   = (short)f2bf(v0 - bf2f(h0)); xl0[i+4] = (short)f2bf(v1 - bf2f(h1));
    xl1[i]   = (short)f2bf(v2 - bf2f(h2)); xl1[i+4] = (short)f2bf(v3 - bf2f(h3));
  }

  const int ct0 = w*4;
  f4 dsh[4];
#pragma unroll
  for (int cc = 0; cc < 4; ++cc) {
    const int ct = ct0 + cc;
    const float* prow = P + (ct*16 + lr)*DH + g*8;
    f4 p0 = *(const f4*)(prow);
    f4 p1 = *(const f4*)(prow + 4);
    f4 p2 = *(const f4*)(prow + 32);
    f4 p3 = *(const f4*)(prow + 36);
    bf8 bh0, bl0, bh1, bl1;
#pragma unroll
    for (int i = 0; i < 4; ++i) {
      unsigned short h0 = f2bf(p0[i]), h1 = f2bf(p1[i]);
      unsigned short h2 = f2bf(p2[i]), h3 = f2bf(p3[i]);
      bh0[i] = (short)h0; bh0[i+4] = (short)h1;
      bh1[i] = (short)h2; bh1[i+4] = (short)h3;
      bl0[i]   = (short)f2bf(p0[i] - bf2f(h0)); bl0[i+4] = (short)f2bf(p1[i] - bf2f(h1));
      bl1[i]   = (short)f2bf(p2[i] - bf2f(h2)); bl1[i+4] = (short)f2bf(p3[i] - bf2f(h3));
    }
    f4 acc = {0.f, 0.f, 0.f, 0.f};
    acc = __builtin_amdgcn_mfma_f32_16x16x32_bf16(xh0, bh0, acc, 0, 0, 0);
    acc = __builtin_amdgcn_mfma_f32_16x16x32_bf16(xh1, bh1, acc, 0, 0, 0);
    acc = __builtin_amdgcn_mfma_f32_16x16x32_bf16(xh0, bl0, acc, 0, 0, 0);
    acc = __builtin_amdgcn_mfma_f32_16x16x32_bf16(xh1, bl1, acc, 0, 0, 0);
    acc = __builtin_amdgcn_mfma_f32_16x16x32_bf16(xl0, bh0, acc, 0, 0, 0);
    acc = __builtin_amdgcn_mfma_f32_16x16x32_bf16(xl1, bh1, acc, 0, 0, 0);
    dsh[cc] = acc;
  }

  f4 mr;
#pragma unroll
  for (int r = 0; r < 4; ++r)
    mr[r] = fmaxf(fmaxf(dsh[0][r], dsh[1][r]), fmaxf(dsh[2][r], dsh[3][r]));
#pragma unroll
  for (int mk = 1; mk <= 8; mk <<= 1) {
#pragma unroll
    for (int r = 0; r < 4; ++r) mr[r] = fmaxf(mr[r], __shfl_xor(mr[r], mk));
  }
  if (lr == 0) {
#pragma unroll
    for (int r = 0; r < 4; ++r) lds[w*16 + 4*g + r] = mr[r];
  }
  __syncthreads();
  float rm[4], sr[4];
#pragma unroll
  for (int r = 0; r < 4; ++r) {
    rm[r] = fmaxf(fmaxf(lds[0*16 + 4*g + r], lds[1*16 + 4*g + r]),
                  fmaxf(lds[2*16 + 4*g + r], lds[3*16 + 4*g + r]));
    sr[r] = __shfl(ss, 4*g + r);
  }

  if (isq) {
    unsigned short* ob = qfb + (size_t)tile*16*NF;
#pragma unroll
    for (int cc = 0; cc < 4; ++cc) {
#pragma unroll
      for (int r = 0; r < 4; ++r)
        ob[(4*g + r)*NF + (ct0 + cc)*16 + lr] =
            f2bf(RATIO*(expf(dsh[cc][r] - (sr[r]*DIAGC + rm[r])) + EPSF));
    }
  } else {
    float* db = dshd + (size_t)tile*16*NF;
#pragma unroll
    for (int cc = 0; cc < 4; ++cc) {
#pragma unroll
      for (int r = 0; r < 4; ++r)
        db[(4*g + r)*NF + (ct0 + cc)*16 + lr] = dsh[cc][r] - sr[r]*DIAGC;
    }
    // per-TILE max (512 entries)
    float tmax = fmaxf(fmaxf(rm[0], rm[1]), fmaxf(rm[2], rm[3]));
    tmax = fmaxf(tmax, __shfl_xor(tmax, 16));
    tmax = fmaxf(tmax, __shfl_xor(tmax, 32));
    if (w == 0 && lane == 0) bmax[tile] = tmax;
  }
}

// ---- k_feat: gmax (512-entry) + exp -> kfb bf16 + kft (m-major) + tile sums ----
__global__ __launch_bounds__(256) void k_feat2(const float* __restrict__ dshd,
    const float* __restrict__ bmax, unsigned short* __restrict__ kfb,
    unsigned short* __restrict__ kft, float* __restrict__ csum) {
  const int u = blockIdx.x, m = threadIdx.x;     // u: 0..511 = h*128 + t
  const int h = u >> 7, t = u & 127;
  __shared__ float red[256];
  red[m] = fmaxf(bmax[m], bmax[m + 256]);
  __syncthreads();
  for (int s = 128; s > 0; s >>= 1) {
    if (m < s) red[m] = fmaxf(red[m], red[m+s]);
    __syncthreads();
  }
  const float gg = red[0];
  const float* db = dshd + (size_t)u*16*NF + m;
  unsigned short* ob = kfb + (size_t)u*16*NF + m;
  float run = 0.f;
  bf8 k0, k1;
#pragma unroll
  for (int r = 0; r < 16; ++r) {
    unsigned short bv = f2bf(RATIO*(expf(db[r*NF] - gg) + EPSF));
    ob[r*NF] = bv;
    if (r < 8) k0[r] = (short)bv; else k1[r-8] = (short)bv;
    run += bf2f(bv);
  }
  csum[(size_t)u*NF + m] = run;
  unsigned short* kt = kft + ((size_t)(h*NF + m))*SEQ + t*16;
  *(bf8*)kt = k0;
  *(bf8*)(kt + 8) = k1;
}

// ---- fused state build + exclusive cumsum -> hi/lo (2-wave split) + csum scan ----
// blocks 0..255: unit (h,et,mt); wave0 walks chunks 0-7, wave1 walks 8-15.
// blocks 256..259: csum exclusive scan for head (b-256), first wave only.
__global__ __launch_bounds__(128) void k_state(
    const unsigned short* __restrict__ vtb, const unsigned short* __restrict__ kft,
    unsigned short* __restrict__ sthi, unsigned short* __restrict__ stlo,
    float* __restrict__ csum) {
  const int bx = blockIdx.x;
  if (bx >= 256) {                       // ---- csum exclusive scan (in place) ----
    if (threadIdx.x >= 64) return;
    const int h = bx - 256;
    const int m0 = threadIdx.x * 4;
    f4 run = {0.f, 0.f, 0.f, 0.f};
#pragma unroll 4
    for (int c = 0; c < 128; ++c) {
      float* p = csum + ((size_t)(h*128 + c))*NF + m0;
      f4 x = *(const f4*)p;
      *(f4*)p = run;
      run += x;
    }
    return;
  }
  __shared__ f4 bridge[64];
  const int wid = threadIdx.x >> 6, lane = threadIdx.x & 63;
  const int lr = lane & 15, g = lane >> 4;
  const int h = bx >> 6, et = (bx >> 4) & 3, mt = bx & 15;

  const unsigned short* vb = vtb + ((size_t)(h*DH + et*16 + lr))*SEQ;
  const unsigned short* kb = kft + ((size_t)(h*NF + mt*16 + lr))*SEQ;

  f4 cum = {0.f, 0.f, 0.f, 0.f};
  f4 loc[8];
  const int c0 = wid*8;
#pragma unroll
  for (int cc = 0; cc < 8; ++cc) {
    const int c = c0 + cc;
    if (wid == 0) {   // global-exclusive prefix known: write directly
      const size_t base = ((size_t)((h*16 + c)*64 + et*16 + 4*g))*NF + mt*16 + lr;
#pragma unroll
      for (int r = 0; r < 4; ++r) {
        unsigned short hi = f2bf(cum[r]);
        sthi[base + (size_t)r*NF] = hi;
        stlo[base + (size_t)r*NF] = f2bf(cum[r] - bf2f(hi));
      }
    } else {
      loc[cc] = cum;  // buffer local prefix
    }
#pragma unroll
    for (int ks = 0; ks < 4; ++ks) {
      const int j0 = c*128 + ks*32 + g*8;
      bf8 xv = *(const bf8*)(vb + j0);
      bf8 ym = *(const bf8*)(kb + j0);
      cum = __builtin_amdgcn_mfma_f32_16x16x32_bf16(xv, ym, cum, 0, 0, 0);
    }
  }
  if (wid == 0) bridge[lane] = cum;      // S(0..7)
  __syncthreads();
  if (wid == 1) {
    f4 s8 = bridge[lane];
#pragma unroll
    for (int cc = 0; cc < 8; ++cc) {
      const int c = 8 + cc;
      f4 val = s8 + loc[cc];
      const size_t base = ((size_t)((h*16 + c)*64 + et*16 + 4*g))*NF + mt*16 + lr;
#pragma unroll
      for (int r = 0; r < 4; ++r) {
        unsigned short hi = f2bf(val[r]);
        sthi[base + (size_t)r*NF] = hi;
        stlo[base + (size_t)r*NF] = f2bf(val[r] - bf2f(hi));
      }
    }
  }
}

// ---- chunked causal attention, 1 wave/block (512 blocks, 2/CU), no barriers ----
// block = (h, t): row-tile t (0..127); chunk c = t>>3; stages jc0..t wave-privately.
__global__ __launch_bounds__(64) void k_attn4(const unsigned short* __restrict__ qpb,
                                              const unsigned short* __restrict__ kfb,
                                              const unsigned short* __restrict__ vtb,
                                              const unsigned short* __restrict__ sthi,
                                              const unsigned short* __restrict__ stlo,
                                              const float* __restrict__ csum,
                                              float* __restrict__ out) {
  const int h = blockIdx.y;
  const int t = blockIdx.x;            // 0..127
  const int c = t >> 3;
  const int jc0 = c*8;
  const int nstage = (t & 7) + 1;
  const int lane = threadIdx.x;
  const int lr = lane & 15, g = lane >> 4;

  __shared__ __align__(16) char smem[18432];
  // Qs [0,8192): 16 rows x 256 m bf16, XOR-swizzled
  char* Ks = smem + 8192;              // 8KB K-tile, XOR-swizzled
  char* Vs = smem + 16384;             // 2KB V-tile

  // ---- prime prologue: q' for this tile's 16 rows; lane owns 4 contiguous m ----
  {
    const int u = h*128 + t;
    f4 run = *(const f4*)(csum + (size_t)u*NF + lane*4);   // exclusive prefix
    const unsigned short* kfp = kfb + ((size_t)(h*SEQ + t*16))*NF + lane*4;
    const unsigned short* qfp = qpb + ((size_t)(h*SEQ + t*16))*NF + lane*4;
#pragma unroll
    for (int r = 0; r < 16; ++r) {
      bf4 kv = *(const bf4*)(kfp + (size_t)r*NF);
      bf4 qv = *(const bf4*)(qfp + (size_t)r*NF);
      unsigned short qp[4];
#pragma unroll
      for (int i = 0; i < 4; ++i) {
        run[i] += bf2f((unsigned short)kv[i]);
        qp[i] = f2bf(bf2f((unsigned short)qv[i]) / run[i]);
      }
      const int byte = (r*512 + lane*8) ^ ((r & 7) << 4);
      *(bf4*)(smem + byte) = *(bf4*)qp;
    }
  }

  // Q' A-fragments from swizzled LDS
  bf8 qf[8];
#pragma unroll
  for (int kb = 0; kb < 8; ++kb) {
    const int byte = (lr*512 + g*16 + kb*64) ^ ((lr & 7) << 4);
    qf[kb] = *(const bf8*)(smem + byte);
  }

  const char* kTile = (const char*)(kfb + (size_t)h*SEQ*NF);
  const char* vTile = (const char*)(vtb + (size_t)h*DH*SEQ);

  // wave-private staging: lane stages 128B of K (8 x 16B) + 32B of V per tile
  int kw[8];
#pragma unroll
  for (int i = 0; i < 8; ++i) {
    const int ko = i*1024 + lane*16;
    kw[i] = ko ^ (((ko >> 9) & 7) << 4);
  }

  f4 sk[8], sv0, sv1;
  {  // issue staging loads for first j-tile (fly under inter-GEMM)
    const char* kt = kTile + (size_t)jc0*8192;
#pragma unroll
    for (int i = 0; i < 8; ++i) sk[i] = *(const f4*)(kt + i*1024 + lane*16);
    const char* vt = vTile + (size_t)lane*4096 + (size_t)jc0*32;
    sv0 = *(const f4*)(vt);
    sv1 = *(const f4*)(vt + 16);
  }

  // ---- inter-chunk: O = q' x cumstate (hi/lo split) ----
  f4 o0 = {0,0,0,0}, o1 = {0,0,0,0}, o2 = {0,0,0,0}, o3 = {0,0,0,0};
  {
    const unsigned short* SH = sthi + ((size_t)((h*16 + c)*64 + lr))*NF + g*8;
    const unsigned short* SL = stlo + ((size_t)((h*16 + c)*64 + lr))*NF + g*8;
#pragma unroll
    for (int ks = 0; ks < 8; ++ks) {
#pragma unroll
      for (int et = 0; et < 4; ++et) {
        bf8 bh = *(const bf8*)(SH + et*16*NF + ks*32);
        bf8 bl = *(const bf8*)(SL + et*16*NF + ks*32);
        f4 acc = (et == 0) ? o0 : (et == 1) ? o1 : (et == 2) ? o2 : o3;
        acc = __builtin_amdgcn_mfma_f32_16x16x32_bf16(qf[ks], bh, acc, 0, 0, 0);
        acc = __builtin_amdgcn_mfma_f32_16x16x32_bf16(qf[ks], bl, acc, 0, 0, 0);
        if (et == 0) o0 = acc; else if (et == 1) o1 = acc; else if (et == 2) o2 = acc; else o3 = acc;
      }
    }
  }

  // ---- intra-chunk causal sweep (wave-private, no barriers) ----
  for (int jj = 0; jj < nstage; ++jj) {
    const int j = jc0 + jj;
#pragma unroll
    for (int i = 0; i < 8; ++i) *(f4*)(Ks + kw[i]) = sk[i];
    *(f4*)(Vs + lane*32) = sv0;
    *(f4*)(Vs + lane*32 + 16) = sv1;
    if (jj + 1 < nstage) {
      const char* kt = kTile + (size_t)(j+1)*8192;
#pragma unroll
      for (int i = 0; i < 8; ++i) sk[i] = *(const f4*)(kt + i*1024 + lane*16);
      const char* vt = vTile + (size_t)lane*4096 + (size_t)(j+1)*32;
      sv0 = *(const f4*)(vt);
      sv1 = *(const f4*)(vt + 16);
    }
    bf8 kcs[8];
#pragma unroll
    for (int kb = 0; kb < 8; ++kb) {
      int off = (lr*512 + kb*64 + g*16) ^ ((lr & 7) << 4);
      kcs[kb] = *(const bf8*)(Ks + off);
    }
    f4 st = {0,0,0,0};
#pragma unroll
    for (int kb = 0; kb < 8; ++kb)
      st = __builtin_amdgcn_mfma_f32_16x16x32_bf16(kcs[kb], qf[kb], st, 0, 0, 0);
    if (j == t) {
#pragma unroll
      for (int rr = 0; rr < 4; ++rr) if (g*4 + rr > lr) st[rr] = 0.f;
    }
    bf8 sb = { (short)f2bf(st[0]), (short)f2bf(st[1]), (short)f2bf(st[2]), (short)f2bf(st[3]),
               (short)0, (short)0, (short)0, (short)0 };
#pragma unroll
    for (int eb = 0; eb < 4; ++eb) {
      bf4 v4 = *(const bf4*)(Vs + (eb*16 + lr)*32 + g*8);
      bf8 vf = { v4[0], v4[1], v4[2], v4[3], (short)0, (short)0, (short)0, (short)0 };
      f4 acc = (eb == 0) ? o0 : (eb == 1) ? o1 : (eb == 2) ? o2 : o3;
      acc = __builtin_amdgcn_mfma_f32_16x16x32_bf16(sb, vf, acc, 0, 0, 0);
      if (eb == 0) o0 = acc; else if (eb == 1) o1 = acc; else if (eb == 2) o2 = acc; else o3 = acc;
    }
  }

  float* ob = out + ((size_t)(h*SEQ + t*16))*DH;
#pragma unroll
  for (int rr = 0; rr < 4; ++rr) {
    ob[(size_t)(4*g + rr)*DH +  0 + lr] = o0[rr];
    ob[(size_t)(4*g + rr)*DH + 16 + lr] = o1[rr];
    ob[(size_t)(4*g + rr)*DH + 32 + lr] = o2[rr];
    ob[(size_t)(4*g + rr)*DH + 48 + lr] = o3[rr];
  }
}

extern "C" void kernel_launch(void* const* d_in, const int* in_sizes, int n_in,
                              void* d_out, int out_size, void* d_ws, size_t ws_size,
                              hipStream_t stream) {
  const float* q = (const float*)d_in[0];
  const float* k = (const float*)d_in[1];
  const float* v = (const float*)d_in[2];
  const float* P = (const float*)d_in[3];
  float* out = (float*)d_out;

  char* ws = (char*)d_ws;                                    // 256 MiB available
  unsigned short* qfb  = (unsigned short*)(ws);              // 4 MB (read-only after proj)
  unsigned short* kfb  = (unsigned short*)(ws + (4u<<20));   // 4 MB
  unsigned short* vtb  = (unsigned short*)(ws + (8u<<20));   // 1 MB
  unsigned short* kft  = (unsigned short*)(ws + (12u<<20));  // 4 MB (m-major kf)
  float* dshd   = (float*)(ws + (16u<<20));                  // 8 MB
  float* bmax   = (float*)(ws + (24u<<20));                  // 2 KB (512 tiles)
  float* csum   = (float*)(ws + (25u<<20));                  // 512 KB
  unsigned short* sthi = (unsigned short*)(ws + (33u<<20));  // 2 MB
  unsigned short* stlo = (unsigned short*)(ws + (36u<<20));  // 2 MB

  k_proj  <<<1152, 256, 0, stream>>>(q, k, v, P, qfb, dshd, bmax, vtb);
  k_feat2 <<<512, 256, 0, stream>>>(dshd, bmax, kfb, kft, csum);
  k_state <<<260, 128, 0, stream>>>(vtb, kft, sthi, stlo, csum);
  k_attn4 <<<dim3(128, NH), 64, 0, stream>>>(qfb, kfb, vtb, sthi, stlo, csum, out);
}

// Round 15
// 52.224 us; speedup vs baseline: 1.4887x; 1.0404x over previous
//
#include <hip/hip_runtime.h>
#include <math.h>

// Problem constants (B=1, H=4, N=2048, D=64, M=256)
#define NH   4
#define SEQ  2048
#define DH   64
#define NF   256
#define ROWS (NH*SEQ)                // 8192
#define DN    0.35355339059327373f   // 64^-0.25
#define DIAGC 0.0625f                // 0.5*DN*DN
#define RATIO 0.0625f                // 1/sqrt(256)
#define EPSF  1e-4f

typedef __attribute__((ext_vector_type(8))) short bf8;
typedef __attribute__((ext_vector_type(4))) short bf4;
typedef __attribute__((ext_vector_type(4))) float f4;

static __device__ __forceinline__ unsigned short f2bf(float x) {
  union { float f; unsigned u; } v; v.f = x;
  unsigned r = v.u + 0x7FFF + ((v.u >> 16) & 1);
  return (unsigned short)(r >> 16);
}
static __device__ __forceinline__ float bf2f(unsigned short b) {
  union { unsigned u; float f; } v; v.u = ((unsigned)b) << 16;
  return v.f;
}

// ---- fused projection (q: full features; k: dsh-diag fp32 + tile max) + V^T ----
// (R14 verbatim)
__global__ __launch_bounds__(256) void k_proj(const float* __restrict__ q,
    const float* __restrict__ k, const float* __restrict__ v,
    const float* __restrict__ P,
    unsigned short* __restrict__ qfb, float* __restrict__ dshd,
    float* __restrict__ bmax, unsigned short* __restrict__ vtb) {
  __shared__ float lds[64*65];
  const int b = blockIdx.x;
  if (b >= 1024) {                       // ---- V transpose: 128 blocks ----
    const int cb = b - 1024;
    const int h = cb >> 5, n0 = (cb & 31) * 64;
    const int tid = threadIdx.x;
    for (int i = tid; i < 4096; i += 256) {
      int n = i >> 6, e = i & 63;
      lds[n*65 + e] = v[((size_t)h*SEQ + n0 + n)*DH + e];
    }
    __syncthreads();
    for (int i = tid; i < 4096; i += 256) {
      int e = i >> 6, n = i & 63;
      vtb[((size_t)h*DH + e)*SEQ + n0 + n] = f2bf(lds[n*65 + e]);
    }
    return;
  }
  const bool isq = b < 512;
  const int tile = isq ? b : b - 512;    // h*128 + t
  const int w = threadIdx.x >> 6, lane = threadIdx.x & 63;
  const int lr = lane & 15, g = lane >> 4;
  const float* x = (isq ? q : k) + (size_t)tile*16*DH;

  f4 a  = *(const f4*)(x + lr*DH + g*8);
  f4 bb = *(const f4*)(x + lr*DH + g*8 + 4);
  f4 c  = *(const f4*)(x + lr*DH + 32 + g*8);
  f4 d  = *(const f4*)(x + lr*DH + 32 + g*8 + 4);
  float ss = 0.f;
#pragma unroll
  for (int i = 0; i < 4; ++i) ss += a[i]*a[i] + bb[i]*bb[i] + c[i]*c[i] + d[i]*d[i];
  ss += __shfl_xor(ss, 16);
  ss += __shfl_xor(ss, 32);              // full sum(x^2) of row lr

  bf8 xh0, xh1, xl0, xl1;
#pragma unroll
  for (int i = 0; i < 4; ++i) {
    float v0 = DN*a[i], v1 = DN*bb[i], v2 = DN*c[i], v3 = DN*d[i];
    unsigned short h0 = f2bf(v0), h1 = f2bf(v1), h2 = f2bf(v2), h3 = f2bf(v3);
    xh0[i] = (short)h0; xh0[i+4] = (short)h1;
    xh1[i] = (short)h2; xh1[i+4] = (short)h3;
    xl0[i]   = (short)f2bf(v0 - bf2f(h0)); xl0[i+4] = (short)f2bf(v1 - bf2f(h1));
    xl1[i]   = (short)f2bf(v2 - bf2f(h2)); xl1[i+4] = (short)f2bf(v3 - bf2f(h3));
  }

  const int ct0 = w*4;
  f4 dsh[4];
#pragma unroll
  for (int cc = 0; cc < 4; ++cc) {
    const int ct = ct0 + cc;
    const float* prow = P + (ct*16 + lr)*DH + g*8;
    f4 p0 = *(const f4*)(prow);
    f4 p1 = *(const f4*)(prow + 4);
    f4 p2 = *(const f4*)(prow + 32);
    f4 p3 = *(const f4*)(prow + 36);
    bf8 bh0, bl0, bh1, bl1;
#pragma unroll
    for (int i = 0; i < 4; ++i) {
      unsigned short h0 = f2bf(p0[i]), h1 = f2bf(p1[i]);
      unsigned short h2 = f2bf(p2[i]), h3 = f2bf(p3[i]);
      bh0[i] = (short)h0; bh0[i+4] = (short)h1;
      bh1[i] = (short)h2; bh1[i+4] = (short)h3;
      bl0[i]   = (short)f2bf(p0[i] - bf2f(h0)); bl0[i+4] = (short)f2bf(p1[i] - bf2f(h1));
      bl1[i]   = (short)f2bf(p2[i] - bf2f(h2)); bl1[i+4] = (short)f2bf(p3[i] - bf2f(h3));
    }
    f4 acc = {0.f, 0.f, 0.f, 0.f};
    acc = __builtin_amdgcn_mfma_f32_16x16x32_bf16(xh0, bh0, acc, 0, 0, 0);
    acc = __builtin_amdgcn_mfma_f32_16x16x32_bf16(xh1, bh1, acc, 0, 0, 0);
    acc = __builtin_amdgcn_mfma_f32_16x16x32_bf16(xh0, bl0, acc, 0, 0, 0);
    acc = __builtin_amdgcn_mfma_f32_16x16x32_bf16(xh1, bl1, acc, 0, 0, 0);
    acc = __builtin_amdgcn_mfma_f32_16x16x32_bf16(xl0, bh0, acc, 0, 0, 0);
    acc = __builtin_amdgcn_mfma_f32_16x16x32_bf16(xl1, bh1, acc, 0, 0, 0);
    dsh[cc] = acc;
  }

  f4 mr;
#pragma unroll
  for (int r = 0; r < 4; ++r)
    mr[r] = fmaxf(fmaxf(dsh[0][r], dsh[1][r]), fmaxf(dsh[2][r], dsh[3][r]));
#pragma unroll
  for (int mk = 1; mk <= 8; mk <<= 1) {
#pragma unroll
    for (int r = 0; r < 4; ++r) mr[r] = fmaxf(mr[r], __shfl_xor(mr[r], mk));
  }
  if (lr == 0) {
#pragma unroll
    for (int r = 0; r < 4; ++r) lds[w*16 + 4*g + r] = mr[r];
  }
  __syncthreads();
  float rm[4], sr[4];
#pragma unroll
  for (int r = 0; r < 4; ++r) {
    rm[r] = fmaxf(fmaxf(lds[0*16 + 4*g + r], lds[1*16 + 4*g + r]),
                  fmaxf(lds[2*16 + 4*g + r], lds[3*16 + 4*g + r]));
    sr[r] = __shfl(ss, 4*g + r);
  }

  if (isq) {
    unsigned short* ob = qfb + (size_t)tile*16*NF;
#pragma unroll
    for (int cc = 0; cc < 4; ++cc) {
#pragma unroll
      for (int r = 0; r < 4; ++r)
        ob[(4*g + r)*NF + (ct0 + cc)*16 + lr] =
            f2bf(RATIO*(expf(dsh[cc][r] - (sr[r]*DIAGC + rm[r])) + EPSF));
    }
  } else {
    float* db = dshd + (size_t)tile*16*NF;
#pragma unroll
    for (int cc = 0; cc < 4; ++cc) {
#pragma unroll
      for (int r = 0; r < 4; ++r)
        db[(4*g + r)*NF + (ct0 + cc)*16 + lr] = dsh[cc][r] - sr[r]*DIAGC;
    }
    float tmax = fmaxf(fmaxf(rm[0], rm[1]), fmaxf(rm[2], rm[3]));
    tmax = fmaxf(tmax, __shfl_xor(tmax, 16));
    tmax = fmaxf(tmax, __shfl_xor(tmax, 32));
    if (w == 0 && lane == 0) bmax[tile] = tmax;
  }
}

// ---- k_feat: gmax (512-entry) + exp -> kfb bf16 + kft (m-major) + tile sums ----
// (R14 verbatim)
__global__ __launch_bounds__(256) void k_feat2(const float* __restrict__ dshd,
    const float* __restrict__ bmax, unsigned short* __restrict__ kfb,
    unsigned short* __restrict__ kft, float* __restrict__ csum) {
  const int u = blockIdx.x, m = threadIdx.x;     // u: 0..511 = h*128 + t
  const int h = u >> 7, t = u & 127;
  __shared__ float red[256];
  red[m] = fmaxf(bmax[m], bmax[m + 256]);
  __syncthreads();
  for (int s = 128; s > 0; s >>= 1) {
    if (m < s) red[m] = fmaxf(red[m], red[m+s]);
    __syncthreads();
  }
  const float gg = red[0];
  const float* db = dshd + (size_t)u*16*NF + m;
  unsigned short* ob = kfb + (size_t)u*16*NF + m;
  float run = 0.f;
  bf8 k0, k1;
#pragma unroll
  for (int r = 0; r < 16; ++r) {
    unsigned short bv = f2bf(RATIO*(expf(db[r*NF] - gg) + EPSF));
    ob[r*NF] = bv;
    if (r < 8) k0[r] = (short)bv; else k1[r-8] = (short)bv;
    run += bf2f(bv);
  }
  csum[(size_t)u*NF + m] = run;
  unsigned short* kt = kft + ((size_t)(h*NF + m))*SEQ + t*16;
  *(bf8*)kt = k0;
  *(bf8*)(kt + 8) = k1;
}

// ---- fused state build + exclusive cumsum -> hi/lo (2-wave split) + csum scan ----
// (R14 verbatim)
__global__ __launch_bounds__(128) void k_state(
    const unsigned short* __restrict__ vtb, const unsigned short* __restrict__ kft,
    unsigned short* __restrict__ sthi, unsigned short* __restrict__ stlo,
    float* __restrict__ csum) {
  const int bx = blockIdx.x;
  if (bx >= 256) {                       // ---- csum exclusive scan (in place) ----
    if (threadIdx.x >= 64) return;
    const int h = bx - 256;
    const int m0 = threadIdx.x * 4;
    f4 run = {0.f, 0.f, 0.f, 0.f};
#pragma unroll 4
    for (int c = 0; c < 128; ++c) {
      float* p = csum + ((size_t)(h*128 + c))*NF + m0;
      f4 x = *(const f4*)p;
      *(f4*)p = run;
      run += x;
    }
    return;
  }
  __shared__ f4 bridge[64];
  const int wid = threadIdx.x >> 6, lane = threadIdx.x & 63;
  const int lr = lane & 15, g = lane >> 4;
  const int h = bx >> 6, et = (bx >> 4) & 3, mt = bx & 15;

  const unsigned short* vb = vtb + ((size_t)(h*DH + et*16 + lr))*SEQ;
  const unsigned short* kb = kft + ((size_t)(h*NF + mt*16 + lr))*SEQ;

  f4 cum = {0.f, 0.f, 0.f, 0.f};
  f4 loc[8];
  const int c0 = wid*8;
#pragma unroll
  for (int cc = 0; cc < 8; ++cc) {
    const int c = c0 + cc;
    if (wid == 0) {
      const size_t base = ((size_t)((h*16 + c)*64 + et*16 + 4*g))*NF + mt*16 + lr;
#pragma unroll
      for (int r = 0; r < 4; ++r) {
        unsigned short hi = f2bf(cum[r]);
        sthi[base + (size_t)r*NF] = hi;
        stlo[base + (size_t)r*NF] = f2bf(cum[r] - bf2f(hi));
      }
    } else {
      loc[cc] = cum;
    }
#pragma unroll
    for (int ks = 0; ks < 4; ++ks) {
      const int j0 = c*128 + ks*32 + g*8;
      bf8 xv = *(const bf8*)(vb + j0);
      bf8 ym = *(const bf8*)(kb + j0);
      cum = __builtin_amdgcn_mfma_f32_16x16x32_bf16(xv, ym, cum, 0, 0, 0);
    }
  }
  if (wid == 0) bridge[lane] = cum;      // S(0..7)
  __syncthreads();
  if (wid == 1) {
    f4 s8 = bridge[lane];
#pragma unroll
    for (int cc = 0; cc < 8; ++cc) {
      const int c = 8 + cc;
      f4 val = s8 + loc[cc];
      const size_t base = ((size_t)((h*16 + c)*64 + et*16 + 4*g))*NF + mt*16 + lr;
#pragma unroll
      for (int r = 0; r < 4; ++r) {
        unsigned short hi = f2bf(val[r]);
        sthi[base + (size_t)r*NF] = hi;
        stlo[base + (size_t)r*NF] = f2bf(val[r] - bf2f(hi));
      }
    }
  }
}

// ---- chunked causal attention: 2 waves/block (wave0 inter, wave1 intra) ----
// block = (h, t): prime split over 128 threads; merge via LDS f4 add.
__global__ __launch_bounds__(128) void k_attn5(const unsigned short* __restrict__ qpb,
                                               const unsigned short* __restrict__ kfb,
                                               const unsigned short* __restrict__ vtb,
                                               const unsigned short* __restrict__ sthi,
                                               const unsigned short* __restrict__ stlo,
                                               const float* __restrict__ csum,
                                               float* __restrict__ out) {
  const int h = blockIdx.y;
  const int t = blockIdx.x;            // 0..127
  const int c = t >> 3;
  const int jc0 = c*8;
  const int nstage = (t & 7) + 1;
  const int tid = threadIdx.x;
  const int wid = tid >> 6, lane = tid & 63;
  const int lr = lane & 15, g = lane >> 4;

  __shared__ __align__(16) char smem[22528];
  // Qs [0,8192): 16 rows x 256 m bf16, XOR-swizzled
  char* Ks = smem + 8192;              // 8KB K-tile (wave1-private)
  char* Vs = smem + 16384;             // 2KB V-tile (wave1-private)
  float* MG = (float*)(smem + 18432);  // 4KB merge buffer [r4][lane][4]

  // ---- prime prologue: 128 threads x 2 m-columns (math identical per column) ----
  {
    const int u = h*128 + t;
    const int m = tid*2;
    float run0 = csum[(size_t)u*NF + m];
    float run1 = csum[(size_t)u*NF + m + 1];
    const unsigned short* kfp = kfb + ((size_t)(h*SEQ + t*16))*NF + m;
    const unsigned short* qfp = qpb + ((size_t)(h*SEQ + t*16))*NF + m;
#pragma unroll
    for (int r = 0; r < 16; ++r) {
      unsigned kv = *(const unsigned*)(kfp + (size_t)r*NF);
      unsigned qv = *(const unsigned*)(qfp + (size_t)r*NF);
      run0 += bf2f((unsigned short)(kv & 0xffff));
      run1 += bf2f((unsigned short)(kv >> 16));
      unsigned short q0 = f2bf(bf2f((unsigned short)(qv & 0xffff)) / run0);
      unsigned short q1 = f2bf(bf2f((unsigned short)(qv >> 16)) / run1);
      const int byte = (r*512 + m*2) ^ ((r & 7) << 4);
      *(unsigned*)(smem + byte) = (unsigned)q0 | ((unsigned)q1 << 16);
    }
  }
  __syncthreads();

  // Q' A-fragments from swizzled LDS (both waves)
  bf8 qf[8];
#pragma unroll
  for (int kb = 0; kb < 8; ++kb) {
    const int byte = (lr*512 + g*16 + kb*64) ^ ((lr & 7) << 4);
    qf[kb] = *(const bf8*)(smem + byte);
  }

  f4 o0 = {0,0,0,0}, o1 = {0,0,0,0}, o2 = {0,0,0,0}, o3 = {0,0,0,0};

  if (wid == 1) {
    // ---- intra-chunk causal sweep (wave-private staging, no barriers) ----
    const char* kTile = (const char*)(kfb + (size_t)h*SEQ*NF);
    const char* vTile = (const char*)(vtb + (size_t)h*DH*SEQ);
    int kw[8];
#pragma unroll
    for (int i = 0; i < 8; ++i) {
      const int ko = i*1024 + lane*16;
      kw[i] = ko ^ (((ko >> 9) & 7) << 4);
    }
    f4 sk[8], sv0, sv1;
    {
      const char* kt = kTile + (size_t)jc0*8192;
#pragma unroll
      for (int i = 0; i < 8; ++i) sk[i] = *(const f4*)(kt + i*1024 + lane*16);
      const char* vt = vTile + (size_t)lane*4096 + (size_t)jc0*32;
      sv0 = *(const f4*)(vt);
      sv1 = *(const f4*)(vt + 16);
    }
    for (int jj = 0; jj < nstage; ++jj) {
      const int j = jc0 + jj;
#pragma unroll
      for (int i = 0; i < 8; ++i) *(f4*)(Ks + kw[i]) = sk[i];
      *(f4*)(Vs + lane*32) = sv0;
      *(f4*)(Vs + lane*32 + 16) = sv1;
      if (jj + 1 < nstage) {
        const char* kt = kTile + (size_t)(j+1)*8192;
#pragma unroll
        for (int i = 0; i < 8; ++i) sk[i] = *(const f4*)(kt + i*1024 + lane*16);
        const char* vt = vTile + (size_t)lane*4096 + (size_t)(j+1)*32;
        sv0 = *(const f4*)(vt);
        sv1 = *(const f4*)(vt + 16);
      }
      bf8 kcs[8];
#pragma unroll
      for (int kb = 0; kb < 8; ++kb) {
        int off = (lr*512 + kb*64 + g*16) ^ ((lr & 7) << 4);
        kcs[kb] = *(const bf8*)(Ks + off);
      }
      f4 st = {0,0,0,0};
#pragma unroll
      for (int kb = 0; kb < 8; ++kb)
        st = __builtin_amdgcn_mfma_f32_16x16x32_bf16(kcs[kb], qf[kb], st, 0, 0, 0);
      if (j == t) {
#pragma unroll
        for (int rr = 0; rr < 4; ++rr) if (g*4 + rr > lr) st[rr] = 0.f;
      }
      bf8 sb = { (short)f2bf(st[0]), (short)f2bf(st[1]), (short)f2bf(st[2]), (short)f2bf(st[3]),
                 (short)0, (short)0, (short)0, (short)0 };
#pragma unroll
      for (int eb = 0; eb < 4; ++eb) {
        bf4 v4 = *(const bf4*)(Vs + (eb*16 + lr)*32 + g*8);
        bf8 vf = { v4[0], v4[1], v4[2], v4[3], (short)0, (short)0, (short)0, (short)0 };
        f4 acc = (eb == 0) ? o0 : (eb == 1) ? o1 : (eb == 2) ? o2 : o3;
        acc = __builtin_amdgcn_mfma_f32_16x16x32_bf16(sb, vf, acc, 0, 0, 0);
        if (eb == 0) o0 = acc; else if (eb == 1) o1 = acc; else if (eb == 2) o2 = acc; else o3 = acc;
      }
    }
    // publish intra partials: [r4][lane] f4 (conflict-free)
    *(f4*)(MG + (0*64 + lane)*4) = o0;
    *(f4*)(MG + (1*64 + lane)*4) = o1;
    *(f4*)(MG + (2*64 + lane)*4) = o2;
    *(f4*)(MG + (3*64 + lane)*4) = o3;
  } else {
    // ---- inter-chunk: O = q' x cumstate (hi/lo split) ----
    const unsigned short* SH = sthi + ((size_t)((h*16 + c)*64 + lr))*NF + g*8;
    const unsigned short* SL = stlo + ((size_t)((h*16 + c)*64 + lr))*NF + g*8;
#pragma unroll
    for (int ks = 0; ks < 8; ++ks) {
#pragma unroll
      for (int et = 0; et < 4; ++et) {
        bf8 bh = *(const bf8*)(SH + et*16*NF + ks*32);
        bf8 bl = *(const bf8*)(SL + et*16*NF + ks*32);
        f4 acc = (et == 0) ? o0 : (et == 1) ? o1 : (et == 2) ? o2 : o3;
        acc = __builtin_amdgcn_mfma_f32_16x16x32_bf16(qf[ks], bh, acc, 0, 0, 0);
        acc = __builtin_amdgcn_mfma_f32_16x16x32_bf16(qf[ks], bl, acc, 0, 0, 0);
        if (et == 0) o0 = acc; else if (et == 1) o1 = acc; else if (et == 2) o2 = acc; else o3 = acc;
      }
    }
  }
  __syncthreads();

  if (wid == 0) {
    o0 += *(const f4*)(MG + (0*64 + lane)*4);
    o1 += *(const f4*)(MG + (1*64 + lane)*4);
    o2 += *(const f4*)(MG + (2*64 + lane)*4);
    o3 += *(const f4*)(MG + (3*64 + lane)*4);
    float* ob = out + ((size_t)(h*SEQ + t*16))*DH;
#pragma unroll
    for (int rr = 0; rr < 4; ++rr) {
      ob[(size_t)(4*g + rr)*DH +  0 + lr] = o0[rr];
      ob[(size_t)(4*g + rr)*DH + 16 + lr] = o1[rr];
      ob[(size_t)(4*g + rr)*DH + 32 + lr] = o2[rr];
      ob[(size_t)(4*g + rr)*DH + 48 + lr] = o3[rr];
    }
  }
}

extern "C" void kernel_launch(void* const* d_in, const int* in_sizes, int n_in,
                              void* d_out, int out_size, void* d_ws, size_t ws_size,
                              hipStream_t stream) {
  const float* q = (const float*)d_in[0];
  const float* k = (const float*)d_in[1];
  const float* v = (const float*)d_in[2];
  const float* P = (const float*)d_in[3];
  float* out = (float*)d_out;

  char* ws = (char*)d_ws;                                    // 256 MiB available
  unsigned short* qfb  = (unsigned short*)(ws);              // 4 MB (read-only after proj)
  unsigned short* kfb  = (unsigned short*)(ws + (4u<<20));   // 4 MB
  unsigned short* vtb  = (unsigned short*)(ws + (8u<<20));   // 1 MB
  unsigned short* kft  = (unsigned short*)(ws + (12u<<20));  // 4 MB (m-major kf)
  float* dshd   = (float*)(ws + (16u<<20));                  // 8 MB
  float* bmax   = (float*)(ws + (24u<<20));                  // 2 KB (512 tiles)
  float* csum   = (float*)(ws + (25u<<20));                  // 512 KB
  unsigned short* sthi = (unsigned short*)(ws + (33u<<20));  // 2 MB
  unsigned short* stlo = (unsigned short*)(ws + (36u<<20));  // 2 MB

  k_proj  <<<1152, 256, 0, stream>>>(q, k, v, P, qfb, dshd, bmax, vtb);
  k_feat2 <<<512, 256, 0, stream>>>(dshd, bmax, kfb, kft, csum);
  k_state <<<260, 128, 0, stream>>>(vtb, kft, sthi, stlo, csum);
  k_attn5 <<<dim3(128, NH), 128, 0, stream>>>(qfb, kfb, vtb, sthi, stlo, csum, out);
}

// Round 16
// 49.442 us; speedup vs baseline: 1.5725x; 1.0563x over previous
//
#include <hip/hip_runtime.h>
#include <math.h>

// Problem constants (B=1, H=4, N=2048, D=64, M=256)
#define NH   4
#define SEQ  2048
#define DH   64
#define NF   256
#define ROWS (NH*SEQ)                // 8192
#define DN    0.35355339059327373f   // 64^-0.25
#define DIAGC 0.0625f                // 0.5*DN*DN
#define RATIO 0.0625f                // 1/sqrt(256)
#define EPSF  1e-4f

typedef __attribute__((ext_vector_type(8))) short bf8;
typedef __attribute__((ext_vector_type(4))) short bf4;
typedef __attribute__((ext_vector_type(4))) float f4;

static __device__ __forceinline__ unsigned short f2bf(float x) {
  union { float f; unsigned u; } v; v.f = x;
  unsigned r = v.u + 0x7FFF + ((v.u >> 16) & 1);
  return (unsigned short)(r >> 16);
}
static __device__ __forceinline__ float bf2f(unsigned short b) {
  union { unsigned u; float f; } v; v.u = ((unsigned)b) << 16;
  return v.f;
}

// ---- fused projection: q-tile AND k-tile per block (shared P split) + V^T ----
// blocks 0..511: tile = h*128+t (both q and k); 512..639: V transpose.
__global__ __launch_bounds__(256) void k_proj(const float* __restrict__ q,
    const float* __restrict__ k, const float* __restrict__ v,
    const float* __restrict__ P,
    unsigned short* __restrict__ qfb, float* __restrict__ dshd,
    float* __restrict__ bmax, unsigned short* __restrict__ vtb) {
  __shared__ float lds[64*65];
  const int b = blockIdx.x;
  if (b >= 512) {                        // ---- V transpose: 128 blocks ----
    const int cb = b - 512;
    const int h = cb >> 5, n0 = (cb & 31) * 64;
    const int tid = threadIdx.x;
    for (int i = tid; i < 4096; i += 256) {
      int n = i >> 6, e = i & 63;
      lds[n*65 + e] = v[((size_t)h*SEQ + n0 + n)*DH + e];
    }
    __syncthreads();
    for (int i = tid; i < 4096; i += 256) {
      int e = i >> 6, n = i & 63;
      vtb[((size_t)h*DH + e)*SEQ + n0 + n] = f2bf(lds[n*65 + e]);
    }
    return;
  }
  const int tile = b;                    // h*128 + t
  const int w = threadIdx.x >> 6, lane = threadIdx.x & 63;
  const int lr = lane & 15, g = lane >> 4;

  // ---- load + split BOTH x-tiles (q and k), row lr, cols g*8 / 32+g*8 ----
  const float* xq = q + (size_t)tile*16*DH;
  const float* xk = k + (size_t)tile*16*DH;
  f4 qa = *(const f4*)(xq + lr*DH + g*8);
  f4 qb = *(const f4*)(xq + lr*DH + g*8 + 4);
  f4 qc = *(const f4*)(xq + lr*DH + 32 + g*8);
  f4 qd = *(const f4*)(xq + lr*DH + 32 + g*8 + 4);
  f4 ka = *(const f4*)(xk + lr*DH + g*8);
  f4 kb_ = *(const f4*)(xk + lr*DH + g*8 + 4);
  f4 kc = *(const f4*)(xk + lr*DH + 32 + g*8);
  f4 kd = *(const f4*)(xk + lr*DH + 32 + g*8 + 4);
  float ssq = 0.f, ssk = 0.f;
#pragma unroll
  for (int i = 0; i < 4; ++i) {
    ssq += qa[i]*qa[i] + qb[i]*qb[i] + qc[i]*qc[i] + qd[i]*qd[i];
    ssk += ka[i]*ka[i] + kb_[i]*kb_[i] + kc[i]*kc[i] + kd[i]*kd[i];
  }
  ssq += __shfl_xor(ssq, 16); ssq += __shfl_xor(ssq, 32);
  ssk += __shfl_xor(ssk, 16); ssk += __shfl_xor(ssk, 32);

  bf8 qh0, qh1, ql0, ql1, kh0, kh1, kl0, kl1;
#pragma unroll
  for (int i = 0; i < 4; ++i) {
    {
      float v0 = DN*qa[i], v1 = DN*qb[i], v2 = DN*qc[i], v3 = DN*qd[i];
      unsigned short h0 = f2bf(v0), h1 = f2bf(v1), h2 = f2bf(v2), h3 = f2bf(v3);
      qh0[i] = (short)h0; qh0[i+4] = (short)h1;
      qh1[i] = (short)h2; qh1[i+4] = (short)h3;
      ql0[i]   = (short)f2bf(v0 - bf2f(h0)); ql0[i+4] = (short)f2bf(v1 - bf2f(h1));
      ql1[i]   = (short)f2bf(v2 - bf2f(h2)); ql1[i+4] = (short)f2bf(v3 - bf2f(h3));
    }
    {
      float v0 = DN*ka[i], v1 = DN*kb_[i], v2 = DN*kc[i], v3 = DN*kd[i];
      unsigned short h0 = f2bf(v0), h1 = f2bf(v1), h2 = f2bf(v2), h3 = f2bf(v3);
      kh0[i] = (short)h0; kh0[i+4] = (short)h1;
      kh1[i] = (short)h2; kh1[i+4] = (short)h3;
      kl0[i]   = (short)f2bf(v0 - bf2f(h0)); kl0[i+4] = (short)f2bf(v1 - bf2f(h1));
      kl1[i]   = (short)f2bf(v2 - bf2f(h2)); kl1[i+4] = (short)f2bf(v3 - bf2f(h3));
    }
  }

  const int ct0 = w*4;
  f4 dshq[4], dshk[4];
#pragma unroll
  for (int cc = 0; cc < 4; ++cc) {
    const int ct = ct0 + cc;
    const float* prow = P + (ct*16 + lr)*DH + g*8;
    f4 p0 = *(const f4*)(prow);
    f4 p1 = *(const f4*)(prow + 4);
    f4 p2 = *(const f4*)(prow + 32);
    f4 p3 = *(const f4*)(prow + 36);
    bf8 bh0, bl0, bh1, bl1;
#pragma unroll
    for (int i = 0; i < 4; ++i) {
      unsigned short h0 = f2bf(p0[i]), h1 = f2bf(p1[i]);
      unsigned short h2 = f2bf(p2[i]), h3 = f2bf(p3[i]);
      bh0[i] = (short)h0; bh0[i+4] = (short)h1;
      bh1[i] = (short)h2; bh1[i+4] = (short)h3;
      bl0[i]   = (short)f2bf(p0[i] - bf2f(h0)); bl0[i+4] = (short)f2bf(p1[i] - bf2f(h1));
      bl1[i]   = (short)f2bf(p2[i] - bf2f(h2)); bl1[i+4] = (short)f2bf(p3[i] - bf2f(h3));
    }
    f4 aq = {0.f, 0.f, 0.f, 0.f};
    aq = __builtin_amdgcn_mfma_f32_16x16x32_bf16(qh0, bh0, aq, 0, 0, 0);
    aq = __builtin_amdgcn_mfma_f32_16x16x32_bf16(qh1, bh1, aq, 0, 0, 0);
    aq = __builtin_amdgcn_mfma_f32_16x16x32_bf16(qh0, bl0, aq, 0, 0, 0);
    aq = __builtin_amdgcn_mfma_f32_16x16x32_bf16(qh1, bl1, aq, 0, 0, 0);
    aq = __builtin_amdgcn_mfma_f32_16x16x32_bf16(ql0, bh0, aq, 0, 0, 0);
    aq = __builtin_amdgcn_mfma_f32_16x16x32_bf16(ql1, bh1, aq, 0, 0, 0);
    dshq[cc] = aq;
    f4 ak = {0.f, 0.f, 0.f, 0.f};
    ak = __builtin_amdgcn_mfma_f32_16x16x32_bf16(kh0, bh0, ak, 0, 0, 0);
    ak = __builtin_amdgcn_mfma_f32_16x16x32_bf16(kh1, bh1, ak, 0, 0, 0);
    ak = __builtin_amdgcn_mfma_f32_16x16x32_bf16(kh0, bl0, ak, 0, 0, 0);
    ak = __builtin_amdgcn_mfma_f32_16x16x32_bf16(kh1, bl1, ak, 0, 0, 0);
    ak = __builtin_amdgcn_mfma_f32_16x16x32_bf16(kl0, bh0, ak, 0, 0, 0);
    ak = __builtin_amdgcn_mfma_f32_16x16x32_bf16(kl1, bh1, ak, 0, 0, 0);
    dshk[cc] = ak;
  }

  // per-row maxes (q and k), cross-lane then cross-wave via disjoint LDS
  f4 mrq, mrk;
#pragma unroll
  for (int r = 0; r < 4; ++r) {
    mrq[r] = fmaxf(fmaxf(dshq[0][r], dshq[1][r]), fmaxf(dshq[2][r], dshq[3][r]));
    mrk[r] = fmaxf(fmaxf(dshk[0][r], dshk[1][r]), fmaxf(dshk[2][r], dshk[3][r]));
  }
#pragma unroll
  for (int mk = 1; mk <= 8; mk <<= 1) {
#pragma unroll
    for (int r = 0; r < 4; ++r) {
      mrq[r] = fmaxf(mrq[r], __shfl_xor(mrq[r], mk));
      mrk[r] = fmaxf(mrk[r], __shfl_xor(mrk[r], mk));
    }
  }
  if (lr == 0) {
#pragma unroll
    for (int r = 0; r < 4; ++r) {
      lds[w*16 + 4*g + r]      = mrq[r];
      lds[64 + w*16 + 4*g + r] = mrk[r];
    }
  }
  __syncthreads();
  float rmq[4], rmk[4], srq[4], srk[4];
#pragma unroll
  for (int r = 0; r < 4; ++r) {
    rmq[r] = fmaxf(fmaxf(lds[0*16 + 4*g + r], lds[1*16 + 4*g + r]),
                   fmaxf(lds[2*16 + 4*g + r], lds[3*16 + 4*g + r]));
    rmk[r] = fmaxf(fmaxf(lds[64 + 0*16 + 4*g + r], lds[64 + 1*16 + 4*g + r]),
                   fmaxf(lds[64 + 2*16 + 4*g + r], lds[64 + 3*16 + 4*g + r]));
    srq[r] = __shfl(ssq, 4*g + r);
    srk[r] = __shfl(ssk, 4*g + r);
  }

  // ---- q epilogue: full features -> qfb ----
  {
    unsigned short* ob = qfb + (size_t)tile*16*NF;
#pragma unroll
    for (int cc = 0; cc < 4; ++cc) {
#pragma unroll
      for (int r = 0; r < 4; ++r)
        ob[(4*g + r)*NF + (ct0 + cc)*16 + lr] =
            f2bf(RATIO*(expf(dshq[cc][r] - (srq[r]*DIAGC + rmq[r])) + EPSF));
    }
  }
  // ---- k epilogue: dsh - diag -> dshd + per-tile max ----
  {
    float* db = dshd + (size_t)tile*16*NF;
#pragma unroll
    for (int cc = 0; cc < 4; ++cc) {
#pragma unroll
      for (int r = 0; r < 4; ++r)
        db[(4*g + r)*NF + (ct0 + cc)*16 + lr] = dshk[cc][r] - srk[r]*DIAGC;
    }
    float tmax = fmaxf(fmaxf(rmk[0], rmk[1]), fmaxf(rmk[2], rmk[3]));
    tmax = fmaxf(tmax, __shfl_xor(tmax, 16));
    tmax = fmaxf(tmax, __shfl_xor(tmax, 32));
    if (w == 0 && lane == 0) bmax[tile] = tmax;
  }
}

// ---- k_feat: gmax (512-entry) + exp -> kfb bf16 + kft (m-major) + tile sums ----
// (R15 verbatim)
__global__ __launch_bounds__(256) void k_feat2(const float* __restrict__ dshd,
    const float* __restrict__ bmax, unsigned short* __restrict__ kfb,
    unsigned short* __restrict__ kft, float* __restrict__ csum) {
  const int u = blockIdx.x, m = threadIdx.x;     // u: 0..511 = h*128 + t
  const int h = u >> 7, t = u & 127;
  __shared__ float red[256];
  red[m] = fmaxf(bmax[m], bmax[m + 256]);
  __syncthreads();
  for (int s = 128; s > 0; s >>= 1) {
    if (m < s) red[m] = fmaxf(red[m], red[m+s]);
    __syncthreads();
  }
  const float gg = red[0];
  const float* db = dshd + (size_t)u*16*NF + m;
  unsigned short* ob = kfb + (size_t)u*16*NF + m;
  float run = 0.f;
  bf8 k0, k1;
#pragma unroll
  for (int r = 0; r < 16; ++r) {
    unsigned short bv = f2bf(RATIO*(expf(db[r*NF] - gg) + EPSF));
    ob[r*NF] = bv;
    if (r < 8) k0[r] = (short)bv; else k1[r-8] = (short)bv;
    run += bf2f(bv);
  }
  csum[(size_t)u*NF + m] = run;
  unsigned short* kt = kft + ((size_t)(h*NF + m))*SEQ + t*16;
  *(bf8*)kt = k0;
  *(bf8*)(kt + 8) = k1;
}

// ---- fused state build + exclusive cumsum -> hi/lo (2-wave split) + csum scan ----
// (R15 verbatim)
__global__ __launch_bounds__(128) void k_state(
    const unsigned short* __restrict__ vtb, const unsigned short* __restrict__ kft,
    unsigned short* __restrict__ sthi, unsigned short* __restrict__ stlo,
    float* __restrict__ csum) {
  const int bx = blockIdx.x;
  if (bx >= 256) {                       // ---- csum exclusive scan (in place) ----
    if (threadIdx.x >= 64) return;
    const int h = bx - 256;
    const int m0 = threadIdx.x * 4;
    f4 run = {0.f, 0.f, 0.f, 0.f};
#pragma unroll 4
    for (int c = 0; c < 128; ++c) {
      float* p = csum + ((size_t)(h*128 + c))*NF + m0;
      f4 x = *(const f4*)p;
      *(f4*)p = run;
      run += x;
    }
    return;
  }
  __shared__ f4 bridge[64];
  const int wid = threadIdx.x >> 6, lane = threadIdx.x & 63;
  const int lr = lane & 15, g = lane >> 4;
  const int h = bx >> 6, et = (bx >> 4) & 3, mt = bx & 15;

  const unsigned short* vb = vtb + ((size_t)(h*DH + et*16 + lr))*SEQ;
  const unsigned short* kb = kft + ((size_t)(h*NF + mt*16 + lr))*SEQ;

  f4 cum = {0.f, 0.f, 0.f, 0.f};
  f4 loc[8];
  const int c0 = wid*8;
#pragma unroll
  for (int cc = 0; cc < 8; ++cc) {
    const int c = c0 + cc;
    if (wid == 0) {
      const size_t base = ((size_t)((h*16 + c)*64 + et*16 + 4*g))*NF + mt*16 + lr;
#pragma unroll
      for (int r = 0; r < 4; ++r) {
        unsigned short hi = f2bf(cum[r]);
        sthi[base + (size_t)r*NF] = hi;
        stlo[base + (size_t)r*NF] = f2bf(cum[r] - bf2f(hi));
      }
    } else {
      loc[cc] = cum;
    }
#pragma unroll
    for (int ks = 0; ks < 4; ++ks) {
      const int j0 = c*128 + ks*32 + g*8;
      bf8 xv = *(const bf8*)(vb + j0);
      bf8 ym = *(const bf8*)(kb + j0);
      cum = __builtin_amdgcn_mfma_f32_16x16x32_bf16(xv, ym, cum, 0, 0, 0);
    }
  }
  if (wid == 0) bridge[lane] = cum;      // S(0..7)
  __syncthreads();
  if (wid == 1) {
    f4 s8 = bridge[lane];
#pragma unroll
    for (int cc = 0; cc < 8; ++cc) {
      const int c = 8 + cc;
      f4 val = s8 + loc[cc];
      const size_t base = ((size_t)((h*16 + c)*64 + et*16 + 4*g))*NF + mt*16 + lr;
#pragma unroll
      for (int r = 0; r < 4; ++r) {
        unsigned short hi = f2bf(val[r]);
        sthi[base + (size_t)r*NF] = hi;
        stlo[base + (size_t)r*NF] = f2bf(val[r] - bf2f(hi));
      }
    }
  }
}

// ---- chunked causal attention: 2 waves/block (wave0 inter, wave1 intra) ----
// (R15 verbatim)
__global__ __launch_bounds__(128) void k_attn5(const unsigned short* __restrict__ qpb,
                                               const unsigned short* __restrict__ kfb,
                                               const unsigned short* __restrict__ vtb,
                                               const unsigned short* __restrict__ sthi,
                                               const unsigned short* __restrict__ stlo,
                                               const float* __restrict__ csum,
                                               float* __restrict__ out) {
  const int h = blockIdx.y;
  const int t = blockIdx.x;            // 0..127
  const int c = t >> 3;
  const int jc0 = c*8;
  const int nstage = (t & 7) + 1;
  const int tid = threadIdx.x;
  const int wid = tid >> 6, lane = tid & 63;
  const int lr = lane & 15, g = lane >> 4;

  __shared__ __align__(16) char smem[22528];
  // Qs [0,8192): 16 rows x 256 m bf16, XOR-swizzled
  char* Ks = smem + 8192;              // 8KB K-tile (wave1-private)
  char* Vs = smem + 16384;             // 2KB V-tile (wave1-private)
  float* MG = (float*)(smem + 18432);  // 4KB merge buffer [r4][lane][4]

  // ---- prime prologue: 128 threads x 2 m-columns ----
  {
    const int u = h*128 + t;
    const int m = tid*2;
    float run0 = csum[(size_t)u*NF + m];
    float run1 = csum[(size_t)u*NF + m + 1];
    const unsigned short* kfp = kfb + ((size_t)(h*SEQ + t*16))*NF + m;
    const unsigned short* qfp = qpb + ((size_t)(h*SEQ + t*16))*NF + m;
#pragma unroll
    for (int r = 0; r < 16; ++r) {
      unsigned kv = *(const unsigned*)(kfp + (size_t)r*NF);
      unsigned qv = *(const unsigned*)(qfp + (size_t)r*NF);
      run0 += bf2f((unsigned short)(kv & 0xffff));
      run1 += bf2f((unsigned short)(kv >> 16));
      unsigned short q0 = f2bf(bf2f((unsigned short)(qv & 0xffff)) / run0);
      unsigned short q1 = f2bf(bf2f((unsigned short)(qv >> 16)) / run1);
      const int byte = (r*512 + m*2) ^ ((r & 7) << 4);
      *(unsigned*)(smem + byte) = (unsigned)q0 | ((unsigned)q1 << 16);
    }
  }
  __syncthreads();

  // Q' A-fragments from swizzled LDS (both waves)
  bf8 qf[8];
#pragma unroll
  for (int kb = 0; kb < 8; ++kb) {
    const int byte = (lr*512 + g*16 + kb*64) ^ ((lr & 7) << 4);
    qf[kb] = *(const bf8*)(smem + byte);
  }

  f4 o0 = {0,0,0,0}, o1 = {0,0,0,0}, o2 = {0,0,0,0}, o3 = {0,0,0,0};

  if (wid == 1) {
    // ---- intra-chunk causal sweep (wave-private staging, no barriers) ----
    const char* kTile = (const char*)(kfb + (size_t)h*SEQ*NF);
    const char* vTile = (const char*)(vtb + (size_t)h*DH*SEQ);
    int kw[8];
#pragma unroll
    for (int i = 0; i < 8; ++i) {
      const int ko = i*1024 + lane*16;
      kw[i] = ko ^ (((ko >> 9) & 7) << 4);
    }
    f4 sk[8], sv0, sv1;
    {
      const char* kt = kTile + (size_t)jc0*8192;
#pragma unroll
      for (int i = 0; i < 8; ++i) sk[i] = *(const f4*)(kt + i*1024 + lane*16);
      const char* vt = vTile + (size_t)lane*4096 + (size_t)jc0*32;
      sv0 = *(const f4*)(vt);
      sv1 = *(const f4*)(vt + 16);
    }
    for (int jj = 0; jj < nstage; ++jj) {
      const int j = jc0 + jj;
#pragma unroll
      for (int i = 0; i < 8; ++i) *(f4*)(Ks + kw[i]) = sk[i];
      *(f4*)(Vs + lane*32) = sv0;
      *(f4*)(Vs + lane*32 + 16) = sv1;
      if (jj + 1 < nstage) {
        const char* kt = kTile + (size_t)(j+1)*8192;
#pragma unroll
        for (int i = 0; i < 8; ++i) sk[i] = *(const f4*)(kt + i*1024 + lane*16);
        const char* vt = vTile + (size_t)lane*4096 + (size_t)(j+1)*32;
        sv0 = *(const f4*)(vt);
        sv1 = *(const f4*)(vt + 16);
      }
      bf8 kcs[8];
#pragma unroll
      for (int kb = 0; kb < 8; ++kb) {
        int off = (lr*512 + kb*64 + g*16) ^ ((lr & 7) << 4);
        kcs[kb] = *(const bf8*)(Ks + off);
      }
      f4 st = {0,0,0,0};
#pragma unroll
      for (int kb = 0; kb < 8; ++kb)
        st = __builtin_amdgcn_mfma_f32_16x16x32_bf16(kcs[kb], qf[kb], st, 0, 0, 0);
      if (j == t) {
#pragma unroll
        for (int rr = 0; rr < 4; ++rr) if (g*4 + rr > lr) st[rr] = 0.f;
      }
      bf8 sb = { (short)f2bf(st[0]), (short)f2bf(st[1]), (short)f2bf(st[2]), (short)f2bf(st[3]),
                 (short)0, (short)0, (short)0, (short)0 };
#pragma unroll
      for (int eb = 0; eb < 4; ++eb) {
        bf4 v4 = *(const bf4*)(Vs + (eb*16 + lr)*32 + g*8);
        bf8 vf = { v4[0], v4[1], v4[2], v4[3], (short)0, (short)0, (short)0, (short)0 };
        f4 acc = (eb == 0) ? o0 : (eb == 1) ? o1 : (eb == 2) ? o2 : o3;
        acc = __builtin_amdgcn_mfma_f32_16x16x32_bf16(sb, vf, acc, 0, 0, 0);
        if (eb == 0) o0 = acc; else if (eb == 1) o1 = acc; else if (eb == 2) o2 = acc; else o3 = acc;
      }
    }
    // publish intra partials: [r4][lane] f4 (conflict-free)
    *(f4*)(MG + (0*64 + lane)*4) = o0;
    *(f4*)(MG + (1*64 + lane)*4) = o1;
    *(f4*)(MG + (2*64 + lane)*4) = o2;
    *(f4*)(MG + (3*64 + lane)*4) = o3;
  } else {
    // ---- inter-chunk: O = q' x cumstate (hi/lo split) ----
    const unsigned short* SH = sthi + ((size_t)((h*16 + c)*64 + lr))*NF + g*8;
    const unsigned short* SL = stlo + ((size_t)((h*16 + c)*64 + lr))*NF + g*8;
#pragma unroll
    for (int ks = 0; ks < 8; ++ks) {
#pragma unroll
      for (int et = 0; et < 4; ++et) {
        bf8 bh = *(const bf8*)(SH + et*16*NF + ks*32);
        bf8 bl = *(const bf8*)(SL + et*16*NF + ks*32);
        f4 acc = (et == 0) ? o0 : (et == 1) ? o1 : (et == 2) ? o2 : o3;
        acc = __builtin_amdgcn_mfma_f32_16x16x32_bf16(qf[ks], bh, acc, 0, 0, 0);
        acc = __builtin_amdgcn_mfma_f32_16x16x32_bf16(qf[ks], bl, acc, 0, 0, 0);
        if (et == 0) o0 = acc; else if (et == 1) o1 = acc; else if (et == 2) o2 = acc; else o3 = acc;
      }
    }
  }
  __syncthreads();

  if (wid == 0) {
    o0 += *(const f4*)(MG + (0*64 + lane)*4);
    o1 += *(const f4*)(MG + (1*64 + lane)*4);
    o2 += *(const f4*)(MG + (2*64 + lane)*4);
    o3 += *(const f4*)(MG + (3*64 + lane)*4);
    float* ob = out + ((size_t)(h*SEQ + t*16))*DH;
#pragma unroll
    for (int rr = 0; rr < 4; ++rr) {
      ob[(size_t)(4*g + rr)*DH +  0 + lr] = o0[rr];
      ob[(size_t)(4*g + rr)*DH + 16 + lr] = o1[rr];
      ob[(size_t)(4*g + rr)*DH + 32 + lr] = o2[rr];
      ob[(size_t)(4*g + rr)*DH + 48 + lr] = o3[rr];
    }
  }
}

extern "C" void kernel_launch(void* const* d_in, const int* in_sizes, int n_in,
                              void* d_out, int out_size, void* d_ws, size_t ws_size,
                              hipStream_t stream) {
  const float* q = (const float*)d_in[0];
  const float* k = (const float*)d_in[1];
  const float* v = (const float*)d_in[2];
  const float* P = (const float*)d_in[3];
  float* out = (float*)d_out;

  char* ws = (char*)d_ws;                                    // 256 MiB available
  unsigned short* qfb  = (unsigned short*)(ws);              // 4 MB (read-only after proj)
  unsigned short* kfb  = (unsigned short*)(ws + (4u<<20));   // 4 MB
  unsigned short* vtb  = (unsigned short*)(ws + (8u<<20));   // 1 MB
  unsigned short* kft  = (unsigned short*)(ws + (12u<<20));  // 4 MB (m-major kf)
  float* dshd   = (float*)(ws + (16u<<20));                  // 8 MB
  float* bmax   = (float*)(ws + (24u<<20));                  // 2 KB (512 tiles)
  float* csum   = (float*)(ws + (25u<<20));                  // 512 KB
  unsigned short* sthi = (unsigned short*)(ws + (33u<<20));  // 2 MB
  unsigned short* stlo = (unsigned short*)(ws + (36u<<20));  // 2 MB

  k_proj  <<<640, 256, 0, stream>>>(q, k, v, P, qfb, dshd, bmax, vtb);
  k_feat2 <<<512, 256, 0, stream>>>(dshd, bmax, kfb, kft, csum);
  k_state <<<260, 128, 0, stream>>>(vtb, kft, sthi, stlo, csum);
  k_attn5 <<<dim3(128, NH), 128, 0, stream>>>(qfb, kfb, vtb, sthi, stlo, csum, out);
}